// Round 22
// baseline (23576.544 us; speedup 1.0000x reference)
//
#include <hip/hip_runtime.h>
#include <math.h>

#define B_ 32
#define N_ 8192
#define G_ 40
#define CB_ 4                 // batches per scatter chunk (stage-1)
#define QB_ 8                 // batches per quarter (trunk pass)

static inline int cdiv(long a, int b){ return (int)((a + (long)b - 1)/b); }

typedef double d4 __attribute__((ext_vector_type(4)));

// ---------------------------------------------------------------------------
// workspace layout (bytes); peak < 101,768,000 proven safe
// ---------------------------------------------------------------------------
#define OFF_S1O   0            // [8,64,8000]  f64 32,768,000 (stage1 -> c2)
#define OFF_S2O   0            // [8,256,1000] f64 16,384,000 (s1o dead)
#define OFF_PART  0            // [4,8,1024,64] f64 16,777,216 (s2o dead, c4 partials)
#define OFF_C4O   16777216     // [8,1024,64]  f64  4,194,304 ends 20,971,520
#define OFF_FC1   20971520     // [32,1024] f64 262,144 (trunk dead at head)
#define OFF_LOG   21233664     // [32,40]   f64  10,240
#define OFF_C2O   32768000     // [8,128,8000] f64 65,536,000 ends 98,304,000
#define OFF_FS    32768000     //   [4,24,64000] f64 49,152,000 (alias, pre-c2)
#define OFF_CNT   81920000     //   [4,64000] f64 2,048,000 (alias, contiguous w/ FS)
#define OFF_C3O   32768000     // [8,512,1000] f64 32,768,000 (c2o dead)
#define OFF_M20   98304000     // [32,8000] f32 1,024,000
#define OFF_M10   99328000     // [32,1000] f32   128,000
#define OFF_S4O   99456000     // [32,8192] f64 2,097,152 ends 101,553,152
#define WS_NEEDED 101560000

// ---------------------------------------------------------------------------
// 1. encode + scatter (fp32 voxel index math; sin/cos + double-angle recurrence)
// ---------------------------------------------------------------------------
__global__ __launch_bounds__(256) void encode_scatter(const float* __restrict__ x,
    double* __restrict__ fsum, double* __restrict__ cnt, int b0)
{
  int tid = blockIdx.x*256 + threadIdx.x;
  if (tid >= CB_*N_) return;
  int bl = tid / N_;
  const float* p = x + ((size_t)b0*N_ + (size_t)tid)*3;
  float c[3] = { p[0], p[1], p[2] };
  int vi[3];
  #pragma unroll
  for (int ci=0; ci<3; ++ci){
    int v = (int)floorf(c[ci] / 0.05f);
    v = v < -20 ? -20 : (v > 19 ? 19 : v);
    vi[ci] = v + 20;
  }
  int lin = (vi[0]*G_ + vi[1])*G_ + vi[2];
  double* fs = fsum + (size_t)bl*24*64000 + lin;
  const float PI_F = 3.14159265358979323846f;
  #pragma unroll
  for (int ci=0; ci<3; ++ci){
    double ang = (double)c[ci] * (double)PI_F;
    double s = sin(ang), co = cos(ang);
    #pragma unroll
    for (int k=0; k<4; ++k){
      atomicAdd(fs + (size_t)(ci*8 + k)    *64000, s);
      atomicAdd(fs + (size_t)(ci*8 + 4 + k)*64000, co);
      double s2 = 2.0*s*co;
      double c2 = co*co - s*s;
      s = s2; co = c2;
    }
  }
  atomicAdd(cnt + (size_t)bl*64000 + lin, 1.0);
}

// pooled mask 40->20 straight from cnt (f32 out, slice pre-offset)
__global__ __launch_bounds__(256) void pool_cnt_m20(const double* __restrict__ cnt,
    float* __restrict__ m20)
{
  int tid = blockIdx.x*256 + threadIdx.x;
  if (tid >= CB_*8000) return;
  int xo = tid % 20; int t = tid/20;
  int yo = t % 20;   t /= 20;
  int zo = t % 20;   int bl = t/20;
  const double* cb = cnt + (size_t)bl*64000;
  float mx = 0.0f;
  for (int dz=0; dz<2; ++dz)
    for (int dy=0; dy<2; ++dy)
      for (int dx=0; dx<2; ++dx)
        if (cb[(size_t)((zo*2+dz)*40 + (yo*2+dy))*40 + (xo*2+dx)] > 0.0) mx = 1.0f;
  m20[(size_t)bl*8000 + (zo*20+yo)*20+xo] = mx;
}

// mask maxpool 2x2x2 f32
__global__ __launch_bounds__(256) void pool_mask_f(const float* __restrict__ m,
    float* __restrict__ mo, int Do, int NB)
{
  long tid = (long)blockIdx.x*256 + threadIdx.x;
  if (tid >= (long)NB*Do*Do*Do) return;
  int Di = Do*2;
  int xo = (int)(tid % Do); long t = tid / Do;
  int yo = (int)(t % Do);   t /= Do;
  int zo = (int)(t % Do);   int b = (int)(t / Do);
  const float* mb = m + (size_t)b*Di*Di*Di;
  float mx = 0.0f;
  for (int dz=0; dz<2; ++dz)
    for (int dy=0; dy<2; ++dy)
      for (int dx=0; dx<2; ++dx)
        mx = fmaxf(mx, mb[(size_t)(zo*2+dz)*Di*Di + (size_t)(yo*2+dy)*Di + (xo*2+dx)]);
  mo[tid] = mx;
}

// ---------------------------------------------------------------------------
// 2. FUSED c1 + LN1 + s1 (r8-audited; fp64 out). One wave per s1 voxel.
// ---------------------------------------------------------------------------
__global__ __launch_bounds__(64) void c1_ln_s1(
    const double* __restrict__ fsum, const double* __restrict__ cnt,
    const float* __restrict__ c1w, const float* __restrict__ c1b,
    const float* __restrict__ g1,  const float* __restrict__ b1,
    const float* __restrict__ s1w, const float* __restrict__ s1b,
    double* __restrict__ out, int lb0)             // out: s1o quarter [8,64,8000]
{
  __shared__ double sfeat[24][64];
  __shared__ double sh1[32][8];
  __shared__ double smask[8];

  int blk = blockIdx.x;
  int xo = blk % 20; int t1 = blk/20;
  int yo = t1 % 20;  t1 /= 20;
  int zo = t1 % 20;  int bl = t1/20;
  int t = threadIdx.x;

  int lz = t >> 4, ly = (t >> 2) & 3, lx = t & 3;
  int gz = zo*2 - 1 + lz, gy = yo*2 - 1 + ly, gx = xo*2 - 1 + lx;
  bool inb = (gz>=0 && gz<40) && (gy>=0 && gy<40) && (gx>=0 && gx<40);
  int vox = (gz*40 + gy)*40 + gx;
  double cv = inb ? cnt[(size_t)bl*64000 + vox] : 0.0;
  double ic = (cv > 0.0) ? 1.0/cv : 0.0;
  const double* fb = fsum + (size_t)bl*24*64000 + (inb ? vox : 0);
  #pragma unroll
  for (int ci=0; ci<24; ++ci)
    sfeat[ci][t] = ic * fb[(size_t)ci*64000];
  if (t < 8){
    int dz=t>>2, dy=(t>>1)&1, dx=t&1;
    double c8 = cnt[(size_t)bl*64000 + (size_t)((zo*2+dz)*40 + (yo*2+dy))*40 + (xo*2+dx)];
    smask[t] = (c8 > 0.0) ? 1.0 : 0.0;
  }
  __syncthreads();

  double pm = fmax(fmax(fmax(smask[0],smask[1]),fmax(smask[2],smask[3])),
                   fmax(fmax(smask[4],smask[5]),fmax(smask[6],smask[7])));
  int ovox = (zo*20 + yo)*20 + xo;
  double* ob = out + (size_t)(lb0+bl)*64*8000 + ovox;
  if (pm == 0.0){
    ob[(size_t)t*8000] = 0.0;
    return;
  }

  int c   = t & 31;
  int svh = t >> 5;
  double acc[4] = {0,0,0,0};
  const float* wc = c1w + (size_t)c*24*27;
  for (int ci=0; ci<24; ++ci){
    const float* wp = wc + ci*27;
    const double* sp = &sfeat[ci][0] + svh*16;
    #pragma unroll
    for (int kz=0; kz<3; ++kz)
    #pragma unroll
    for (int ky=0; ky<3; ++ky)
    #pragma unroll
    for (int kx=0; kx<3; ++kx){
      double wv = (double)wp[(kz*3+ky)*3+kx];
      const double* q = sp + kz*16 + ky*4 + kx;
      acc[0] += wv * q[0];
      acc[1] += wv * q[1];
      acc[2] += wv * q[4];
      acc[3] += wv * q[5];
    }
  }
  double bias = (double)c1b[c], gc = (double)g1[c], bc = (double)b1[c];
  double h[4], rs1[4], rs2[4];
  #pragma unroll
  for (int i=0;i<4;++i){
    h[i] = (acc[i] + bias) * smask[svh*4+i];
    rs1[i] = h[i]; rs2[i] = h[i]*h[i];
  }
  #pragma unroll
  for (int off=1; off<32; off<<=1){
    #pragma unroll
    for (int i=0;i<4;++i){
      rs1[i] += __shfl_xor(rs1[i], off);
      rs2[i] += __shfl_xor(rs2[i], off);
    }
  }
  #pragma unroll
  for (int i=0;i<4;++i){
    double mu  = rs1[i]*(1.0/32.0);
    double var = fmax(rs2[i]*(1.0/32.0) - mu*mu, 0.0);
    double r   = 1.0/sqrt(var + 1e-5);
    double yv  = ((h[i]-mu)*r*gc + bc) * smask[svh*4+i];
    sh1[c][svh*4+i] = fmax(yv, 0.0);
  }
  __syncthreads();

  const float* wo = s1w + (size_t)t*256;
  double s = 0.0;
  #pragma unroll
  for (int ci=0; ci<32; ++ci){
    #pragma unroll
    for (int sv=0; sv<8; ++sv)
      s += (double)wo[ci*8+sv] * sh1[ci][sv];
  }
  ob[(size_t)t*8000] = fmax(s + (double)s1b[t], 0.0);
}

// ---------------------------------------------------------------------------
// 3. implicit-GEMM 3^3 SAME conv via fp64 MFMA. 32 couts per wave via TWO
//    accumulators SHARING the B operand. TI=4 (17.3 KB LDS -> 8 blocks/CU)
//    and bank-spread LDS layout (io-stride 135 = 7 mod 32, cc-stride 27).
//    Runtime D-layout detect.
// ---------------------------------------------------------------------------
__device__ __forceinline__ double Pf_(int i,int k){ return (double)(1 + i + 31*k); }
__device__ __forceinline__ double Qf_(int k,int j){ return (double)(2 + 3*j + 7*k); }
__device__ __forceinline__ double Rf_(int m,int n){
  double s = 0.0;
  for (int k=0;k<4;++k) s += Pf_(m,k)*Qf_(k,n);
  return s;
}

template<int TI>
__global__ __launch_bounds__(256) void conv_mfma(
    const double* __restrict__ in, const float* __restrict__ w,
    const float* __restrict__ bias, double* __restrict__ out,
    int NB, int Cin, int Cout, int D)
{
  // layout: wl[(io*(TI+1) + cc)*27 + tap]
  __shared__ float wl[32*(TI+1)*27];
  int spat = D*D*D;
  const int BV = 64;                    // 4 waves x 16 voxels
  int nvt = (spat + BV - 1) / BV;
  int bid = blockIdx.x;
  int vt4 = bid % nvt; int t1 = bid / nvt;
  int cot = t1 % (Cout/32); int b = t1 / (Cout/32);
  int wid = threadIdx.x >> 6;
  int lane = threadIdx.x & 63;
  int li = lane & 15, lk = lane >> 4;

  // ---- hardware D-layout self-detect (wave-uniform, constant) ----
  d4 z = {0.0,0.0,0.0,0.0};
  d4 det = __builtin_amdgcn_mfma_f64_16x16x4f64(Pf_(li,lk), Qf_(lk,li), z, 0,0,0);
  bool m2 = true, m3 = true;
  #pragma unroll
  for (int r=0;r<4;++r){
    m2 = m2 && (fabs(det[r] - Rf_(lk+4*r, li)) < 1e-3);   // D[lk+4r][li]
    m3 = m3 && (fabs(det[r] - Rf_(li, 4*lk+r)) < 1e-3);   // D[li][4lk+r]
  }
  int mode = __all(m2) ? 2 : (__all(m3) ? 3 : 1);

  int vbase = vt4*BV + wid*16;
  int vox = vbase + li;
  bool vok = vox < spat;
  int vc = vok ? vox : 0;
  int vz = vc/(D*D), vy = (vc/D)%D, vx = vc%D;

  const double* inb = in + (size_t)b*Cin*spat;
  d4 acc0 = {0.0,0.0,0.0,0.0};
  d4 acc1 = {0.0,0.0,0.0,0.0};

  for (int ci0 = 0; ci0 < Cin; ci0 += TI){
    for (int idx = threadIdx.x; idx < TI*32*27; idx += 256){
      int tap = idx % 27; int t2 = idx / 27;
      int io = t2 % 32; int cc = t2 / 32;
      wl[(io*(TI+1) + cc)*27 + tap] =
          w[((size_t)(cot*32+io)*Cin + (ci0+cc))*27 + tap];
    }
    __syncthreads();
    const double* ipk = inb + (size_t)(ci0 + lk)*spat;
    #pragma unroll
    for (int dz = 0; dz < 3; ++dz){
      #pragma unroll
      for (int dy = 0; dy < 3; ++dy){
        #pragma unroll
        for (int dx = 0; dx < 3; ++dx){
          int tap = (dz*3+dy)*3+dx;
          int zi = vz+dz-1, yi = vy+dy-1, xi = vx+dx-1;
          bool ok = vok && zi>=0 && zi<D && yi>=0 && yi<D && xi>=0 && xi<D;
          int so = ok ? (zi*D + yi)*D + xi : 0;
          #pragma unroll
          for (int kq = 0; kq < TI/4; ++kq){
            double bv = ok ? ipk[(size_t)(kq*4)*spat + so] : 0.0;
            int cc = kq*4 + lk;
            double a0 = (double)wl[(li*(TI+1) + cc)*27 + tap];        // A[co li]
            double a1 = (double)wl[((16+li)*(TI+1) + cc)*27 + tap];   // A[co 16+li]
            acc0 = __builtin_amdgcn_mfma_f64_16x16x4f64(a0, bv, acc0, 0, 0, 0);
            acc1 = __builtin_amdgcn_mfma_f64_16x16x4f64(a1, bv, acc1, 0, 0, 0);
          }
        }
      }
    }
    __syncthreads();
  }

  size_t obb = (size_t)b*Cout*spat;
  if (mode == 2){
    if (vok){
      #pragma unroll
      for (int r = 0; r < 4; ++r){
        int co0 = cot*32 + lk + 4*r;                 // D[lk+4r][li]
        int co1 = co0 + 16;
        out[obb + (size_t)co0*spat + vox] = acc0[r] + (double)bias[co0];
        out[obb + (size_t)co1*spat + vox] = acc1[r] + (double)bias[co1];
      }
    }
  } else if (mode == 3){
    int co0 = cot*32 + li;                           // D[li][4lk+r]
    int co1 = co0 + 16;
    double bv0 = (double)bias[co0], bv1 = (double)bias[co1];
    #pragma unroll
    for (int r = 0; r < 4; ++r){
      int vw = vbase + 4*lk + r;
      if (vw < spat){
        out[obb + (size_t)co0*spat + vw] = acc0[r] + bv0;
        out[obb + (size_t)co1*spat + vw] = acc1[r] + bv1;
      }
    }
  } else {
    if (vok){
      #pragma unroll
      for (int r = 0; r < 4; ++r){
        int co0 = cot*32 + 4*lk + r;                 // fallback
        int co1 = co0 + 16;
        out[obb + (size_t)co0*spat + vox] = acc0[r] + (double)bias[co0];
        out[obb + (size_t)co1*spat + vox] = acc1[r] + (double)bias[co1];
      }
    }
  }
}

static void launch_cmf(const double* in, const float* w, const float* bias,
                       double* out, int Cin, int Cout, int D, int NB, hipStream_t st)
{
  int spat = D*D*D;
  int nvt = (spat + 63)/64;
  int grid = NB * (Cout/32) * nvt;
  conv_mfma<4><<<grid,256,0,st>>>(in, w, bias, out, NB, Cin, Cout, D);
}

// ---------------------------------------------------------------------------
// 4. conv3d, LDS-staged f32 weights, fp64 VALU math (s2, c4)
// ---------------------------------------------------------------------------
template<int K, int S, int P, int XT, int CT, int CGB, int TI,
         bool MMUL, bool RELU_, bool PARTIAL>
__global__ __launch_bounds__(256) void conv_lds(
    const double* __restrict__ in, const float* __restrict__ w,
    const float* __restrict__ bias, const float* __restrict__ mask,
    double* __restrict__ out, int NB, int Cin, int Din, int Cout, int Dout,
    int ncic, int cich)
{
  const int K3 = K*K*K;
  const int SP = 256/CGB;
  const int NR = (XT-1)*S + K;
  __shared__ float wl[CGB*CT][TI*K3];

  int tilesx = (Dout + XT - 1)/XT;
  int spat = tilesx*Dout*Dout;
  int nsb = (spat + SP - 1)/SP;
  int bid = blockIdx.x;
  int cic = 0;
  if (PARTIAL){ cic = bid % ncic; bid /= ncic; }
  int sb = bid % nsb;  int t1 = bid / nsb;
  int ncgo = Cout/(CT*CGB);
  int cgo = t1 % ncgo; int b = t1 / ncgo;
  int ciBeg = PARTIAL ? cic*cich : 0;
  int ciEnd = PARTIAL ? ciBeg + cich : Cin;

  int lc = threadIdx.x / SP;
  int sp = threadIdx.x % SP;
  int sidx = sb*SP + sp;
  bool act = sidx < spat;
  int sc = act ? sidx : 0;
  int tx = sc % tilesx;
  int y  = (sc/tilesx) % Dout;
  int z  = sc/(tilesx*Dout);
  int x0 = tx*XT;
  int co0 = (cgo*CGB + lc)*CT;

  int DD = Din*Din;
  const double* inb = in + (size_t)b*Cin*Din*DD;
  const int wcs = Cin*K3;

  double acc[CT][XT];
  #pragma unroll
  for (int c=0;c<CT;++c){
    double bv = PARTIAL ? 0.0 : (double)bias[co0+c];
    #pragma unroll
    for (int i=0;i<XT;++i) acc[c][i]=bv;
  }

  for (int ci0=ciBeg; ci0<ciEnd; ci0+=TI){
    const int cnt_w = CGB*CT*TI*K3;
    for (int idx = threadIdx.x; idx < cnt_w; idx += 256){
      int k  = idx % K3; int t2 = idx / K3;
      int cil= t2 % TI;  int cr = t2 / TI;
      int co = cgo*CGB*CT + cr;
      float v = 0.0f;
      if (ci0+cil < ciEnd) v = w[(size_t)co*wcs + (size_t)(ci0+cil)*K3 + k];
      wl[cr][cil*K3 + k] = v;
    }
    __syncthreads();
    int tmax = min(TI, ciEnd-ci0);
    for (int cil=0; cil<tmax; ++cil){
      const double* inc = inb + (size_t)(ci0+cil)*Din*DD;
      #pragma unroll
      for (int dz=0; dz<K; ++dz){
        int zi = z*S + dz - P;
        if (zi < 0 || zi >= Din) continue;
        #pragma unroll
        for (int dy=0; dy<K; ++dy){
          int yi = y*S + dy - P;
          if (yi < 0 || yi >= Din) continue;
          const double* row = inc + (size_t)zi*DD + (size_t)yi*Din;
          double rv[NR];
          #pragma unroll
          for (int r=0;r<NR;++r){
            int xi = x0*S + r - P;
            rv[r] = (xi>=0 && xi<Din) ? row[xi] : 0.0;
          }
          #pragma unroll
          for (int dx=0; dx<K; ++dx){
            double wv[CT];
            #pragma unroll
            for (int c=0;c<CT;++c)
              wv[c] = (double)wl[lc*CT+c][cil*K3 + (dz*K+dy)*K + dx];
            #pragma unroll
            for (int i=0;i<XT;++i)
              #pragma unroll
              for (int c=0;c<CT;++c) acc[c][i] += wv[c]*rv[i*S+dx];
          }
        }
      }
    }
    __syncthreads();
  }

  if (act){
    int oDD = Dout*Dout;
    size_t chunk_off = PARTIAL ? (size_t)cic*NB*Cout*Dout*oDD : 0;
    size_t ob = chunk_off + (size_t)b*Cout*Dout*oDD + (size_t)z*oDD + (size_t)y*Dout;
    #pragma unroll
    for (int i=0;i<XT;++i){
      int xo = x0+i;
      if (xo >= Dout) continue;
      double mv = 1.0;
      if (MMUL) mv = (double)mask[(size_t)b*Dout*oDD + (size_t)z*oDD + (size_t)y*Dout + xo];
      #pragma unroll
      for (int c=0;c<CT;++c){
        double v = acc[c][i];
        if (MMUL) v *= mv;
        if (RELU_) v = fmax(v,0.0);
        out[ob + (size_t)(co0+c)*Dout*oDD + xo] = v;
      }
    }
  }
}

template<int K,int S,int P,int XT,int CT,int CGB,int TI,bool MM,bool RL,bool PART>
static void launch_conv(const double* in, const float* w, const float* bias,
                        const float* mask, double* out,
                        int Cin, int Din, int Cout, int Dout, int NB,
                        int ncic, hipStream_t st)
{
  const int SP = 256/CGB;
  int tilesx = (Dout+XT-1)/XT;
  int spat = tilesx*Dout*Dout;
  int nsb = (spat + SP - 1)/SP;
  long grid = (long)(PART?ncic:1) * NB * (Cout/(CT*CGB)) * nsb;
  conv_lds<K,S,P,XT,CT,CGB,TI,MM,RL,PART><<<(int)grid,256,0,st>>>(
      in,w,bias,mask,out,NB,Cin,Din,Cout,Dout,ncic,Cin/(PART?ncic:1));
}

// sum NCIC c4 partials + bias + relu -> c4o
__global__ __launch_bounds__(256) void c4_reduce(const double* __restrict__ part,
    const float* __restrict__ bias, double* __restrict__ out, int NB, int ncic)
{
  long tid = (long)blockIdx.x*256 + threadIdx.x;
  long total = (long)NB*1024*64;
  if (tid >= total) return;
  int co = (int)((tid >> 6) & 1023);
  double s = (double)bias[co];
  for (int c=0; c<ncic; ++c) s += part[(size_t)c*total + tid];
  out[tid] = fmax(s, 0.0);
}

// ---------------------------------------------------------------------------
// 5. s4: one wave per (b,co), 8 outputs
// ---------------------------------------------------------------------------
__global__ __launch_bounds__(256) void s4_wave(const double* __restrict__ c4o,
    const float* __restrict__ w, const float* __restrict__ bias,
    double* __restrict__ out, int NB)
{
  long gt = (long)blockIdx.x*256 + threadIdx.x;
  int wid = (int)(gt >> 6);
  int lane = threadIdx.x & 63;
  if (wid >= NB*1024) return;
  int co = wid & 1023; int b = wid >> 10;
  const double* ib = c4o + (size_t)b*1024*64;
  const float* wp = w + (size_t)co*8192;
  double acc[8] = {0,0,0,0,0,0,0,0};
  for (int k=lane; k<8192; k+=64){
    double wv = (double)wp[k];
    int ci = k>>3, sv = k&7;
    int dz = sv>>2, dy=(sv>>1)&1, dx=sv&1;
    const double* icp = ib + (size_t)ci*64;
    #pragma unroll
    for (int v=0; v<8; ++v){
      int zo=v>>2, yo=(v>>1)&1, xo=v&1;
      acc[v] += wv * icp[((zo*2+dz)*4+(yo*2+dy))*4 + (xo*2+dx)];
    }
  }
  #pragma unroll
  for (int v=0;v<8;++v){
    double a = acc[v];
    #pragma unroll
    for (int off=32;off>0;off>>=1) a += __shfl_down(a, off);
    if (lane==0) out[((size_t)b*1024+co)*8 + v] = a + (double)bias[co];
  }
}

// ---------------------------------------------------------------------------
// 6. channel LayerNorm: fp64 x, f32 params/mask, two-pass (applies mask)
// ---------------------------------------------------------------------------
__global__ __launch_bounds__(256) void ln_chan_d(double* __restrict__ x,
    const float* __restrict__ g, const float* __restrict__ bt,
    const float* __restrict__ mask, int C, int V, int NB)
{
  long tid = (long)blockIdx.x*256 + threadIdx.x;
  if (tid >= (long)NB*V) return;
  int b = (int)(tid / V);
  int v = (int)(tid - (long)b*V);
  double* xp = x + (size_t)b*C*V + v;
  double s = 0.0;
  for (int c=0; c<C; ++c) s += xp[(size_t)c*V];
  double mu = s / C;
  double s2 = 0.0;
  for (int c=0; c<C; ++c){ double d = xp[(size_t)c*V] - mu; s2 += d*d; }
  double r  = 1.0/sqrt(s2 / C + 1e-5);
  double mv = (double)mask[tid];
  for (int c=0; c<C; ++c){
    double yv = ((xp[(size_t)c*V] - mu) * r * (double)g[c] + (double)bt[c]) * mv;
    xp[(size_t)c*V] = fmax(yv, 0.0);
  }
}

// ---------------------------------------------------------------------------
// 7. head — fp64
// ---------------------------------------------------------------------------
__global__ __launch_bounds__(256) void ln_vec(double* __restrict__ h,
    const float* __restrict__ g, const float* __restrict__ bt)
{
  __shared__ double red[256];
  int b = blockIdx.x, t = threadIdx.x;
  double* hp = h + (size_t)b*8192;
  double s = 0.0;
  for (int k=t; k<8192; k+=256) s += hp[k];
  red[t] = s; __syncthreads();
  for (int o=128; o>0; o>>=1){ if (t<o) red[t] += red[t+o]; __syncthreads(); }
  double mu = red[0] / 8192.0;  __syncthreads();
  double s2 = 0.0;
  for (int k=t; k<8192; k+=256){ double d = hp[k]-mu; s2 += d*d; }
  red[t] = s2; __syncthreads();
  for (int o=128; o>0; o>>=1){ if (t<o) red[t] += red[t+o]; __syncthreads(); }
  double r = 1.0/sqrt(red[0]/8192.0 + 1e-5);
  for (int k=t; k<8192; k+=256)
    hp[k] = fmax((hp[k]-mu)*r*(double)g[k] + (double)bt[k], 0.0);
}

__global__ __launch_bounds__(256) void fc_wave(const double* __restrict__ h,
    const float* __restrict__ w, const float* __restrict__ bias,
    double* __restrict__ out, int Kdim, int O, int relu)
{
  long gt = (long)blockIdx.x*256 + threadIdx.x;
  int wid  = (int)(gt >> 6);
  int lane = threadIdx.x & 63;
  if (wid >= B_*O) return;
  int b = wid / O, o = wid - b*O;
  const double* hp = h + (size_t)b*Kdim;
  const float*  wp = w + (size_t)o*Kdim;
  double acc = 0.0;
  for (int k=lane; k<Kdim; k+=64) acc += hp[k]*(double)wp[k];
  #pragma unroll
  for (int off=32; off>0; off>>=1) acc += __shfl_down(acc, off);
  if (lane == 0){
    double v = acc + (double)bias[o];
    if (relu) v = fmax(v, 0.0);
    out[(size_t)b*O + o] = v;
  }
}

__global__ __launch_bounds__(64) void lsm_out(const double* __restrict__ logits,
    float* __restrict__ out)
{
  int b = threadIdx.x;
  if (b >= B_) return;
  const double* lp = logits + (size_t)b*40;
  double m = lp[0];
  for (int i=1; i<40; ++i) m = lp[i] > m ? lp[i] : m;
  double s = 0.0;
  for (int i=0; i<40; ++i) s += exp(lp[i]-m);
  double ls = log(s);
  for (int i=0; i<40; ++i) out[(size_t)b*40+i] = (float)(lp[i] - m - ls);
}

// ---------------------------------------------------------------------------
extern "C" void kernel_launch(void* const* d_in, const int* in_sizes, int n_in,
                              void* d_out, int out_size, void* d_ws, size_t ws_size,
                              hipStream_t stream)
{
  if (ws_size < (size_t)WS_NEEDED) return;

  const float* x   = (const float*)d_in[0];
  const float* c1w = (const float*)d_in[1];  const float* c1b = (const float*)d_in[2];
  const float* g1  = (const float*)d_in[3];  const float* b1  = (const float*)d_in[4];
  const float* s1w = (const float*)d_in[5];  const float* s1b = (const float*)d_in[6];
  const float* c2w = (const float*)d_in[7];  const float* c2b = (const float*)d_in[8];
  const float* g2  = (const float*)d_in[9];  const float* b2  = (const float*)d_in[10];
  const float* s2w = (const float*)d_in[11]; const float* s2b = (const float*)d_in[12];
  const float* c3w = (const float*)d_in[13]; const float* c3b = (const float*)d_in[14];
  const float* g3  = (const float*)d_in[15]; const float* b3  = (const float*)d_in[16];
  const float* c4w = (const float*)d_in[17]; const float* c4b = (const float*)d_in[18];
  const float* s4w = (const float*)d_in[19]; const float* s4b = (const float*)d_in[20];
  const float* g4  = (const float*)d_in[21]; const float* b4  = (const float*)d_in[22];
  const float* f1w = (const float*)d_in[23]; const float* f1b = (const float*)d_in[24];
  const float* f2w = (const float*)d_in[25]; const float* f2b = (const float*)d_in[26];

  char* ws = (char*)d_ws;
  double* s1o = (double*)(ws + OFF_S1O);
  double* s2o = (double*)(ws + OFF_S2O);
  double* part= (double*)(ws + OFF_PART);
  double* c4o = (double*)(ws + OFF_C4O);
  double* c2o = (double*)(ws + OFF_C2O);
  double* c3o = (double*)(ws + OFF_C3O);
  double* fsum= (double*)(ws + OFF_FS);
  double* cnt = (double*)(ws + OFF_CNT);
  float*  m20 = (float*)(ws + OFF_M20);
  float*  m10 = (float*)(ws + OFF_M10);
  double* s4o = (double*)(ws + OFF_S4O);
  double* fc1o= (double*)(ws + OFF_FC1);
  double* logd= (double*)(ws + OFF_LOG);

  for (int q = 0; q < 4; ++q){
    int qb0 = q * QB_;

    // ---- stage 1: 2 scatter-chunks of 4 batches -> fused c1/LN1/s1 ----
    for (int sc = 0; sc < QB_/CB_; ++sc){
      int b0  = qb0 + sc*CB_;
      int lb0 = sc*CB_;
      hipMemsetAsync(ws + OFF_FS, 0, (size_t)CB_*24*64000*8 + (size_t)CB_*64000*8, stream);
      encode_scatter<<<cdiv((long)CB_*N_,256),256,0,stream>>>(x, fsum, cnt, b0);
      pool_cnt_m20  <<<cdiv((long)CB_*8000,256),256,0,stream>>>(cnt, m20 + (size_t)b0*8000);
      c1_ln_s1<<<CB_*8000, 64, 0, stream>>>(fsum, cnt, c1w, c1b, g1, b1,
                                            s1w, s1b, s1o, lb0);
    }
    pool_mask_f<<<cdiv((long)QB_*1000,256),256,0,stream>>>(
        m20 + (size_t)qb0*8000, m10 + (size_t)qb0*1000, 10, QB_);

    // ---- stage 2: c2 via fp64 MFMA (32 couts/wave, shared B) + LN2 + s2 ----
    launch_cmf(s1o, c2w, c2b, c2o, 64, 128, 20, QB_, stream);
    ln_chan_d<<<cdiv((long)QB_*8000,256),256,0,stream>>>(
        c2o, g2, b2, m20 + (size_t)qb0*8000, 128, 8000, QB_);
    launch_conv<2,2,0, 2,8, 1,128, true,true,false>(c2o, s2w, s2b,
        m10 + (size_t)qb0*1000, s2o, 128, 20, 256, 10, QB_, 1, stream);

    // ---- stage 3: c3 via fp64 MFMA (32 couts/wave, shared B) + LN3 ----
    launch_cmf(s2o, c3w, c3b, c3o, 256, 512, 10, QB_, stream);
    ln_chan_d<<<cdiv((long)QB_*1000,256),256,0,stream>>>(
        c3o, g3, b3, m10 + (size_t)qb0*1000, 512, 1000, QB_);

    // ---- stage 4: c4 partial (4 Cin-chunks) + reduce(relu) ; s4 ----
    launch_conv<3,2,0, 2,4, 8,8, false,false,true>(c3o, c4w, c4b, nullptr,
        part, 512, 10, 1024, 4, QB_, 4, stream);
    c4_reduce<<<cdiv((long)QB_*1024*64,256),256,0,stream>>>(part, c4b, c4o, QB_, 4);
    s4_wave<<<cdiv((long)QB_*1024*64,256),256,0,stream>>>(
        c4o, s4w, s4b, s4o + (size_t)qb0*8192, QB_);
  }

  // ---- head (fp64) ----
  ln_vec<<<B_,256,0,stream>>>(s4o, g4, b4);
  fc_wave<<<cdiv((long)B_*1024*64,256),256,0,stream>>>(s4o, f1w, f1b, fc1o, 8192, 1024, 1);
  fc_wave<<<cdiv((long)B_*40*64,256),  256,0,stream>>>(fc1o, f2w, f2b, logd, 1024, 40, 0);
  lsm_out<<<1,64,0,stream>>>(logd, (float*)d_out);
}

// Round 23
// 22745.399 us; speedup vs baseline: 1.0365x; 1.0365x over previous
//
#include <hip/hip_runtime.h>
#include <math.h>

#define B_ 32
#define N_ 8192
#define G_ 40
#define CB_ 4                 // batches per scatter chunk (stage-1)
#define QB_ 8                 // batches per quarter (trunk pass)

static inline int cdiv(long a, int b){ return (int)((a + (long)b - 1)/b); }

typedef double d4 __attribute__((ext_vector_type(4)));

// ---------------------------------------------------------------------------
// workspace layout (bytes); peak < 101,768,000 proven safe
// ---------------------------------------------------------------------------
#define OFF_S1O   0            // [8,64,8000]  f64 32,768,000 (stage1 -> c2)
#define OFF_S2O   0            // [8,256,1000] f64 16,384,000 (s1o dead)
#define OFF_PART  0            // [4,8,1024,64] f64 16,777,216 (s2o dead, c4 partials)
#define OFF_C4O   16777216     // [8,1024,64]  f64  4,194,304 ends 20,971,520
#define OFF_FC1   20971520     // [32,1024] f64 262,144 (trunk dead at head)
#define OFF_LOG   21233664     // [32,40]   f64  10,240
#define OFF_C2O   32768000     // [8,128,8000] f64 65,536,000 ends 98,304,000
#define OFF_FS    32768000     //   [4,24,64000] f64 49,152,000 (alias, pre-c2)
#define OFF_CNT   81920000     //   [4,64000] f64 2,048,000 (alias, contiguous w/ FS)
#define OFF_C3O   32768000     // [8,512,1000] f64 32,768,000 (c2o dead)
#define OFF_M20   98304000     // [32,8000] f32 1,024,000
#define OFF_M10   99328000     // [32,1000] f32   128,000
#define OFF_S4O   99456000     // [32,8192] f64 2,097,152 ends 101,553,152
#define WS_NEEDED 101560000

// ---------------------------------------------------------------------------
// 1. encode + scatter (fp32 voxel index math; sin/cos + double-angle recurrence)
// ---------------------------------------------------------------------------
__global__ __launch_bounds__(256) void encode_scatter(const float* __restrict__ x,
    double* __restrict__ fsum, double* __restrict__ cnt, int b0)
{
  int tid = blockIdx.x*256 + threadIdx.x;
  if (tid >= CB_*N_) return;
  int bl = tid / N_;
  const float* p = x + ((size_t)b0*N_ + (size_t)tid)*3;
  float c[3] = { p[0], p[1], p[2] };
  int vi[3];
  #pragma unroll
  for (int ci=0; ci<3; ++ci){
    int v = (int)floorf(c[ci] / 0.05f);
    v = v < -20 ? -20 : (v > 19 ? 19 : v);
    vi[ci] = v + 20;
  }
  int lin = (vi[0]*G_ + vi[1])*G_ + vi[2];
  double* fs = fsum + (size_t)bl*24*64000 + lin;
  const float PI_F = 3.14159265358979323846f;
  #pragma unroll
  for (int ci=0; ci<3; ++ci){
    double ang = (double)c[ci] * (double)PI_F;
    double s = sin(ang), co = cos(ang);
    #pragma unroll
    for (int k=0; k<4; ++k){
      atomicAdd(fs + (size_t)(ci*8 + k)    *64000, s);
      atomicAdd(fs + (size_t)(ci*8 + 4 + k)*64000, co);
      double s2 = 2.0*s*co;
      double c2 = co*co - s*s;
      s = s2; co = c2;
    }
  }
  atomicAdd(cnt + (size_t)bl*64000 + lin, 1.0);
}

// pooled mask 40->20 straight from cnt (f32 out, slice pre-offset)
__global__ __launch_bounds__(256) void pool_cnt_m20(const double* __restrict__ cnt,
    float* __restrict__ m20)
{
  int tid = blockIdx.x*256 + threadIdx.x;
  if (tid >= CB_*8000) return;
  int xo = tid % 20; int t = tid/20;
  int yo = t % 20;   t /= 20;
  int zo = t % 20;   int bl = t/20;
  const double* cb = cnt + (size_t)bl*64000;
  float mx = 0.0f;
  for (int dz=0; dz<2; ++dz)
    for (int dy=0; dy<2; ++dy)
      for (int dx=0; dx<2; ++dx)
        if (cb[(size_t)((zo*2+dz)*40 + (yo*2+dy))*40 + (xo*2+dx)] > 0.0) mx = 1.0f;
  m20[(size_t)bl*8000 + (zo*20+yo)*20+xo] = mx;
}

// mask maxpool 2x2x2 f32
__global__ __launch_bounds__(256) void pool_mask_f(const float* __restrict__ m,
    float* __restrict__ mo, int Do, int NB)
{
  long tid = (long)blockIdx.x*256 + threadIdx.x;
  if (tid >= (long)NB*Do*Do*Do) return;
  int Di = Do*2;
  int xo = (int)(tid % Do); long t = tid / Do;
  int yo = (int)(t % Do);   t /= Do;
  int zo = (int)(t % Do);   int b = (int)(t / Do);
  const float* mb = m + (size_t)b*Di*Di*Di;
  float mx = 0.0f;
  for (int dz=0; dz<2; ++dz)
    for (int dy=0; dy<2; ++dy)
      for (int dx=0; dx<2; ++dx)
        mx = fmaxf(mx, mb[(size_t)(zo*2+dz)*Di*Di + (size_t)(yo*2+dy)*Di + (xo*2+dx)]);
  mo[tid] = mx;
}

// ---------------------------------------------------------------------------
// 2. FUSED c1 + LN1 + s1 (r8-audited; fp64 out). One wave per s1 voxel.
// ---------------------------------------------------------------------------
__global__ __launch_bounds__(64) void c1_ln_s1(
    const double* __restrict__ fsum, const double* __restrict__ cnt,
    const float* __restrict__ c1w, const float* __restrict__ c1b,
    const float* __restrict__ g1,  const float* __restrict__ b1,
    const float* __restrict__ s1w, const float* __restrict__ s1b,
    double* __restrict__ out, int lb0)             // out: s1o quarter [8,64,8000]
{
  __shared__ double sfeat[24][64];
  __shared__ double sh1[32][8];
  __shared__ double smask[8];

  int blk = blockIdx.x;
  int xo = blk % 20; int t1 = blk/20;
  int yo = t1 % 20;  t1 /= 20;
  int zo = t1 % 20;  int bl = t1/20;
  int t = threadIdx.x;

  int lz = t >> 4, ly = (t >> 2) & 3, lx = t & 3;
  int gz = zo*2 - 1 + lz, gy = yo*2 - 1 + ly, gx = xo*2 - 1 + lx;
  bool inb = (gz>=0 && gz<40) && (gy>=0 && gy<40) && (gx>=0 && gx<40);
  int vox = (gz*40 + gy)*40 + gx;
  double cv = inb ? cnt[(size_t)bl*64000 + vox] : 0.0;
  double ic = (cv > 0.0) ? 1.0/cv : 0.0;
  const double* fb = fsum + (size_t)bl*24*64000 + (inb ? vox : 0);
  #pragma unroll
  for (int ci=0; ci<24; ++ci)
    sfeat[ci][t] = ic * fb[(size_t)ci*64000];
  if (t < 8){
    int dz=t>>2, dy=(t>>1)&1, dx=t&1;
    double c8 = cnt[(size_t)bl*64000 + (size_t)((zo*2+dz)*40 + (yo*2+dy))*40 + (xo*2+dx)];
    smask[t] = (c8 > 0.0) ? 1.0 : 0.0;
  }
  __syncthreads();

  double pm = fmax(fmax(fmax(smask[0],smask[1]),fmax(smask[2],smask[3])),
                   fmax(fmax(smask[4],smask[5]),fmax(smask[6],smask[7])));
  int ovox = (zo*20 + yo)*20 + xo;
  double* ob = out + (size_t)(lb0+bl)*64*8000 + ovox;
  if (pm == 0.0){
    ob[(size_t)t*8000] = 0.0;
    return;
  }

  int c   = t & 31;
  int svh = t >> 5;
  double acc[4] = {0,0,0,0};
  const float* wc = c1w + (size_t)c*24*27;
  for (int ci=0; ci<24; ++ci){
    const float* wp = wc + ci*27;
    const double* sp = &sfeat[ci][0] + svh*16;
    #pragma unroll
    for (int kz=0; kz<3; ++kz)
    #pragma unroll
    for (int ky=0; ky<3; ++ky)
    #pragma unroll
    for (int kx=0; kx<3; ++kx){
      double wv = (double)wp[(kz*3+ky)*3+kx];
      const double* q = sp + kz*16 + ky*4 + kx;
      acc[0] += wv * q[0];
      acc[1] += wv * q[1];
      acc[2] += wv * q[4];
      acc[3] += wv * q[5];
    }
  }
  double bias = (double)c1b[c], gc = (double)g1[c], bc = (double)b1[c];
  double h[4], rs1[4], rs2[4];
  #pragma unroll
  for (int i=0;i<4;++i){
    h[i] = (acc[i] + bias) * smask[svh*4+i];
    rs1[i] = h[i]; rs2[i] = h[i]*h[i];
  }
  #pragma unroll
  for (int off=1; off<32; off<<=1){
    #pragma unroll
    for (int i=0;i<4;++i){
      rs1[i] += __shfl_xor(rs1[i], off);
      rs2[i] += __shfl_xor(rs2[i], off);
    }
  }
  #pragma unroll
  for (int i=0;i<4;++i){
    double mu  = rs1[i]*(1.0/32.0);
    double var = fmax(rs2[i]*(1.0/32.0) - mu*mu, 0.0);
    double r   = 1.0/sqrt(var + 1e-5);
    double yv  = ((h[i]-mu)*r*gc + bc) * smask[svh*4+i];
    sh1[c][svh*4+i] = fmax(yv, 0.0);
  }
  __syncthreads();

  const float* wo = s1w + (size_t)t*256;
  double s = 0.0;
  #pragma unroll
  for (int ci=0; ci<32; ++ci){
    #pragma unroll
    for (int sv=0; sv<8; ++sv)
      s += (double)wo[ci*8+sv] * sh1[ci][sv];
  }
  ob[(size_t)t*8000] = fmax(s + (double)s1b[t], 0.0);
}

// ---------------------------------------------------------------------------
// 3. implicit-GEMM 3^3 SAME conv via fp64 MFMA. 32 couts per wave via TWO
//    accumulators SHARING the B operand (free 2nd chain: no extra loads).
//    TI=8 keeps the 32-cout weight tile at 27.6 KB. Runtime D-layout detect.
//    (r21-verified best configuration.)
// ---------------------------------------------------------------------------
__device__ __forceinline__ double Pf_(int i,int k){ return (double)(1 + i + 31*k); }
__device__ __forceinline__ double Qf_(int k,int j){ return (double)(2 + 3*j + 7*k); }
__device__ __forceinline__ double Rf_(int m,int n){
  double s = 0.0;
  for (int k=0;k<4;++k) s += Pf_(m,k)*Qf_(k,n);
  return s;
}

template<int TI>
__global__ __launch_bounds__(256) void conv_mfma(
    const double* __restrict__ in, const float* __restrict__ w,
    const float* __restrict__ bias, double* __restrict__ out,
    int NB, int Cin, int Cout, int D)
{
  __shared__ float wl[TI*32*27];        // [cc][io(32)][tap]
  int spat = D*D*D;
  const int BV = 64;                    // 4 waves x 16 voxels
  int nvt = (spat + BV - 1) / BV;
  int bid = blockIdx.x;
  int vt4 = bid % nvt; int t1 = bid / nvt;
  int cot = t1 % (Cout/32); int b = t1 / (Cout/32);
  int wid = threadIdx.x >> 6;
  int lane = threadIdx.x & 63;
  int li = lane & 15, lk = lane >> 4;

  // ---- hardware D-layout self-detect (wave-uniform, constant) ----
  d4 z = {0.0,0.0,0.0,0.0};
  d4 det = __builtin_amdgcn_mfma_f64_16x16x4f64(Pf_(li,lk), Qf_(lk,li), z, 0,0,0);
  bool m2 = true, m3 = true;
  #pragma unroll
  for (int r=0;r<4;++r){
    m2 = m2 && (fabs(det[r] - Rf_(lk+4*r, li)) < 1e-3);   // D[lk+4r][li]
    m3 = m3 && (fabs(det[r] - Rf_(li, 4*lk+r)) < 1e-3);   // D[li][4lk+r]
  }
  int mode = __all(m2) ? 2 : (__all(m3) ? 3 : 1);

  int vbase = vt4*BV + wid*16;
  int vox = vbase + li;
  bool vok = vox < spat;
  int vc = vok ? vox : 0;
  int vz = vc/(D*D), vy = (vc/D)%D, vx = vc%D;

  const double* inb = in + (size_t)b*Cin*spat;
  d4 acc0 = {0.0,0.0,0.0,0.0};
  d4 acc1 = {0.0,0.0,0.0,0.0};

  for (int ci0 = 0; ci0 < Cin; ci0 += TI){
    for (int idx = threadIdx.x; idx < TI*32*27; idx += 256){
      int tap = idx % 27; int t2 = idx / 27;
      int io = t2 % 32; int cc = t2 / 32;
      wl[(cc*32 + io)*27 + tap] =
          w[((size_t)(cot*32+io)*Cin + (ci0+cc))*27 + tap];
    }
    __syncthreads();
    const double* ipk = inb + (size_t)(ci0 + lk)*spat;
    #pragma unroll
    for (int dz = 0; dz < 3; ++dz){
      #pragma unroll
      for (int dy = 0; dy < 3; ++dy){
        #pragma unroll
        for (int dx = 0; dx < 3; ++dx){
          int tap = (dz*3+dy)*3+dx;
          int zi = vz+dz-1, yi = vy+dy-1, xi = vx+dx-1;
          bool ok = vok && zi>=0 && zi<D && yi>=0 && yi<D && xi>=0 && xi<D;
          int so = ok ? (zi*D + yi)*D + xi : 0;
          #pragma unroll
          for (int kq = 0; kq < TI/4; ++kq){
            double bv = ok ? ipk[(size_t)(kq*4)*spat + so] : 0.0;
            double a0 = (double)wl[((kq*4+lk)*32 + li)*27 + tap];       // A[co li]
            double a1 = (double)wl[((kq*4+lk)*32 + 16 + li)*27 + tap];  // A[co 16+li]
            acc0 = __builtin_amdgcn_mfma_f64_16x16x4f64(a0, bv, acc0, 0, 0, 0);
            acc1 = __builtin_amdgcn_mfma_f64_16x16x4f64(a1, bv, acc1, 0, 0, 0);
          }
        }
      }
    }
    __syncthreads();
  }

  size_t obb = (size_t)b*Cout*spat;
  if (mode == 2){
    if (vok){
      #pragma unroll
      for (int r = 0; r < 4; ++r){
        int co0 = cot*32 + lk + 4*r;                 // D[lk+4r][li]
        int co1 = co0 + 16;
        out[obb + (size_t)co0*spat + vox] = acc0[r] + (double)bias[co0];
        out[obb + (size_t)co1*spat + vox] = acc1[r] + (double)bias[co1];
      }
    }
  } else if (mode == 3){
    int co0 = cot*32 + li;                           // D[li][4lk+r]
    int co1 = co0 + 16;
    double bv0 = (double)bias[co0], bv1 = (double)bias[co1];
    #pragma unroll
    for (int r = 0; r < 4; ++r){
      int vw = vbase + 4*lk + r;
      if (vw < spat){
        out[obb + (size_t)co0*spat + vw] = acc0[r] + bv0;
        out[obb + (size_t)co1*spat + vw] = acc1[r] + bv1;
      }
    }
  } else {
    if (vok){
      #pragma unroll
      for (int r = 0; r < 4; ++r){
        int co0 = cot*32 + 4*lk + r;                 // fallback
        int co1 = co0 + 16;
        out[obb + (size_t)co0*spat + vox] = acc0[r] + (double)bias[co0];
        out[obb + (size_t)co1*spat + vox] = acc1[r] + (double)bias[co1];
      }
    }
  }
}

static void launch_cmf(const double* in, const float* w, const float* bias,
                       double* out, int Cin, int Cout, int D, int NB, hipStream_t st)
{
  int spat = D*D*D;
  int nvt = (spat + 63)/64;
  int grid = NB * (Cout/32) * nvt;
  conv_mfma<8><<<grid,256,0,st>>>(in, w, bias, out, NB, Cin, Cout, D);
}

// ---------------------------------------------------------------------------
// 4. conv3d, LDS-staged f32 weights, fp64 VALU math (s2, c4)
// ---------------------------------------------------------------------------
template<int K, int S, int P, int XT, int CT, int CGB, int TI,
         bool MMUL, bool RELU_, bool PARTIAL>
__global__ __launch_bounds__(256) void conv_lds(
    const double* __restrict__ in, const float* __restrict__ w,
    const float* __restrict__ bias, const float* __restrict__ mask,
    double* __restrict__ out, int NB, int Cin, int Din, int Cout, int Dout,
    int ncic, int cich)
{
  const int K3 = K*K*K;
  const int SP = 256/CGB;
  const int NR = (XT-1)*S + K;
  __shared__ float wl[CGB*CT][TI*K3];

  int tilesx = (Dout + XT - 1)/XT;
  int spat = tilesx*Dout*Dout;
  int nsb = (spat + SP - 1)/SP;
  int bid = blockIdx.x;
  int cic = 0;
  if (PARTIAL){ cic = bid % ncic; bid /= ncic; }
  int sb = bid % nsb;  int t1 = bid / nsb;
  int ncgo = Cout/(CT*CGB);
  int cgo = t1 % ncgo; int b = t1 / ncgo;
  int ciBeg = PARTIAL ? cic*cich : 0;
  int ciEnd = PARTIAL ? ciBeg + cich : Cin;

  int lc = threadIdx.x / SP;
  int sp = threadIdx.x % SP;
  int sidx = sb*SP + sp;
  bool act = sidx < spat;
  int sc = act ? sidx : 0;
  int tx = sc % tilesx;
  int y  = (sc/tilesx) % Dout;
  int z  = sc/(tilesx*Dout);
  int x0 = tx*XT;
  int co0 = (cgo*CGB + lc)*CT;

  int DD = Din*Din;
  const double* inb = in + (size_t)b*Cin*Din*DD;
  const int wcs = Cin*K3;

  double acc[CT][XT];
  #pragma unroll
  for (int c=0;c<CT;++c){
    double bv = PARTIAL ? 0.0 : (double)bias[co0+c];
    #pragma unroll
    for (int i=0;i<XT;++i) acc[c][i]=bv;
  }

  for (int ci0=ciBeg; ci0<ciEnd; ci0+=TI){
    const int cnt_w = CGB*CT*TI*K3;
    for (int idx = threadIdx.x; idx < cnt_w; idx += 256){
      int k  = idx % K3; int t2 = idx / K3;
      int cil= t2 % TI;  int cr = t2 / TI;
      int co = cgo*CGB*CT + cr;
      float v = 0.0f;
      if (ci0+cil < ciEnd) v = w[(size_t)co*wcs + (size_t)(ci0+cil)*K3 + k];
      wl[cr][cil*K3 + k] = v;
    }
    __syncthreads();
    int tmax = min(TI, ciEnd-ci0);
    for (int cil=0; cil<tmax; ++cil){
      const double* inc = inb + (size_t)(ci0+cil)*Din*DD;
      #pragma unroll
      for (int dz=0; dz<K; ++dz){
        int zi = z*S + dz - P;
        if (zi < 0 || zi >= Din) continue;
        #pragma unroll
        for (int dy=0; dy<K; ++dy){
          int yi = y*S + dy - P;
          if (yi < 0 || yi >= Din) continue;
          const double* row = inc + (size_t)zi*DD + (size_t)yi*Din;
          double rv[NR];
          #pragma unroll
          for (int r=0;r<NR;++r){
            int xi = x0*S + r - P;
            rv[r] = (xi>=0 && xi<Din) ? row[xi] : 0.0;
          }
          #pragma unroll
          for (int dx=0; dx<K; ++dx){
            double wv[CT];
            #pragma unroll
            for (int c=0;c<CT;++c)
              wv[c] = (double)wl[lc*CT+c][cil*K3 + (dz*K+dy)*K + dx];
            #pragma unroll
            for (int i=0;i<XT;++i)
              #pragma unroll
              for (int c=0;c<CT;++c) acc[c][i] += wv[c]*rv[i*S+dx];
          }
        }
      }
    }
    __syncthreads();
  }

  if (act){
    int oDD = Dout*Dout;
    size_t chunk_off = PARTIAL ? (size_t)cic*NB*Cout*Dout*oDD : 0;
    size_t ob = chunk_off + (size_t)b*Cout*Dout*oDD + (size_t)z*oDD + (size_t)y*Dout;
    #pragma unroll
    for (int i=0;i<XT;++i){
      int xo = x0+i;
      if (xo >= Dout) continue;
      double mv = 1.0;
      if (MMUL) mv = (double)mask[(size_t)b*Dout*oDD + (size_t)z*oDD + (size_t)y*Dout + xo];
      #pragma unroll
      for (int c=0;c<CT;++c){
        double v = acc[c][i];
        if (MMUL) v *= mv;
        if (RELU_) v = fmax(v,0.0);
        out[ob + (size_t)(co0+c)*Dout*oDD + xo] = v;
      }
    }
  }
}

template<int K,int S,int P,int XT,int CT,int CGB,int TI,bool MM,bool RL,bool PART>
static void launch_conv(const double* in, const float* w, const float* bias,
                        const float* mask, double* out,
                        int Cin, int Din, int Cout, int Dout, int NB,
                        int ncic, hipStream_t st)
{
  const int SP = 256/CGB;
  int tilesx = (Dout+XT-1)/XT;
  int spat = tilesx*Dout*Dout;
  int nsb = (spat + SP - 1)/SP;
  long grid = (long)(PART?ncic:1) * NB * (Cout/(CT*CGB)) * nsb;
  conv_lds<K,S,P,XT,CT,CGB,TI,MM,RL,PART><<<(int)grid,256,0,st>>>(
      in,w,bias,mask,out,NB,Cin,Din,Cout,Dout,ncic,Cin/(PART?ncic:1));
}

// sum NCIC c4 partials + bias + relu -> c4o
__global__ __launch_bounds__(256) void c4_reduce(const double* __restrict__ part,
    const float* __restrict__ bias, double* __restrict__ out, int NB, int ncic)
{
  long tid = (long)blockIdx.x*256 + threadIdx.x;
  long total = (long)NB*1024*64;
  if (tid >= total) return;
  int co = (int)((tid >> 6) & 1023);
  double s = (double)bias[co];
  for (int c=0; c<ncic; ++c) s += part[(size_t)c*total + tid];
  out[tid] = fmax(s, 0.0);
}

// ---------------------------------------------------------------------------
// 5. s4: one wave per (b,co), 8 outputs
// ---------------------------------------------------------------------------
__global__ __launch_bounds__(256) void s4_wave(const double* __restrict__ c4o,
    const float* __restrict__ w, const float* __restrict__ bias,
    double* __restrict__ out, int NB)
{
  long gt = (long)blockIdx.x*256 + threadIdx.x;
  int wid = (int)(gt >> 6);
  int lane = threadIdx.x & 63;
  if (wid >= NB*1024) return;
  int co = wid & 1023; int b = wid >> 10;
  const double* ib = c4o + (size_t)b*1024*64;
  const float* wp = w + (size_t)co*8192;
  double acc[8] = {0,0,0,0,0,0,0,0};
  for (int k=lane; k<8192; k+=64){
    double wv = (double)wp[k];
    int ci = k>>3, sv = k&7;
    int dz = sv>>2, dy=(sv>>1)&1, dx=sv&1;
    const double* icp = ib + (size_t)ci*64;
    #pragma unroll
    for (int v=0; v<8; ++v){
      int zo=v>>2, yo=(v>>1)&1, xo=v&1;
      acc[v] += wv * icp[((zo*2+dz)*4+(yo*2+dy))*4 + (xo*2+dx)];
    }
  }
  #pragma unroll
  for (int v=0;v<8;++v){
    double a = acc[v];
    #pragma unroll
    for (int off=32;off>0;off>>=1) a += __shfl_down(a, off);
    if (lane==0) out[((size_t)b*1024+co)*8 + v] = a + (double)bias[co];
  }
}

// ---------------------------------------------------------------------------
// 6. channel LayerNorm: fp64 x, f32 params/mask, two-pass (applies mask)
// ---------------------------------------------------------------------------
__global__ __launch_bounds__(256) void ln_chan_d(double* __restrict__ x,
    const float* __restrict__ g, const float* __restrict__ bt,
    const float* __restrict__ mask, int C, int V, int NB)
{
  long tid = (long)blockIdx.x*256 + threadIdx.x;
  if (tid >= (long)NB*V) return;
  int b = (int)(tid / V);
  int v = (int)(tid - (long)b*V);
  double* xp = x + (size_t)b*C*V + v;
  double s = 0.0;
  for (int c=0; c<C; ++c) s += xp[(size_t)c*V];
  double mu = s / C;
  double s2 = 0.0;
  for (int c=0; c<C; ++c){ double d = xp[(size_t)c*V] - mu; s2 += d*d; }
  double r  = 1.0/sqrt(s2 / C + 1e-5);
  double mv = (double)mask[tid];
  for (int c=0; c<C; ++c){
    double yv = ((xp[(size_t)c*V] - mu) * r * (double)g[c] + (double)bt[c]) * mv;
    xp[(size_t)c*V] = fmax(yv, 0.0);
  }
}

// ---------------------------------------------------------------------------
// 7. head — fp64
// ---------------------------------------------------------------------------
__global__ __launch_bounds__(256) void ln_vec(double* __restrict__ h,
    const float* __restrict__ g, const float* __restrict__ bt)
{
  __shared__ double red[256];
  int b = blockIdx.x, t = threadIdx.x;
  double* hp = h + (size_t)b*8192;
  double s = 0.0;
  for (int k=t; k<8192; k+=256) s += hp[k];
  red[t] = s; __syncthreads();
  for (int o=128; o>0; o>>=1){ if (t<o) red[t] += red[t+o]; __syncthreads(); }
  double mu = red[0] / 8192.0;  __syncthreads();
  double s2 = 0.0;
  for (int k=t; k<8192; k+=256){ double d = hp[k]-mu; s2 += d*d; }
  red[t] = s2; __syncthreads();
  for (int o=128; o>0; o>>=1){ if (t<o) red[t] += red[t+o]; __syncthreads(); }
  double r = 1.0/sqrt(red[0]/8192.0 + 1e-5);
  for (int k=t; k<8192; k+=256)
    hp[k] = fmax((hp[k]-mu)*r*(double)g[k] + (double)bt[k], 0.0);
}

__global__ __launch_bounds__(256) void fc_wave(const double* __restrict__ h,
    const float* __restrict__ w, const float* __restrict__ bias,
    double* __restrict__ out, int Kdim, int O, int relu)
{
  long gt = (long)blockIdx.x*256 + threadIdx.x;
  int wid  = (int)(gt >> 6);
  int lane = threadIdx.x & 63;
  if (wid >= B_*O) return;
  int b = wid / O, o = wid - b*O;
  const double* hp = h + (size_t)b*Kdim;
  const float*  wp = w + (size_t)o*Kdim;
  double acc = 0.0;
  for (int k=lane; k<Kdim; k+=64) acc += hp[k]*(double)wp[k];
  #pragma unroll
  for (int off=32; off>0; off>>=1) acc += __shfl_down(acc, off);
  if (lane == 0){
    double v = acc + (double)bias[o];
    if (relu) v = fmax(v, 0.0);
    out[(size_t)b*O + o] = v;
  }
}

__global__ __launch_bounds__(64) void lsm_out(const double* __restrict__ logits,
    float* __restrict__ out)
{
  int b = threadIdx.x;
  if (b >= B_) return;
  const double* lp = logits + (size_t)b*40;
  double m = lp[0];
  for (int i=1; i<40; ++i) m = lp[i] > m ? lp[i] : m;
  double s = 0.0;
  for (int i=0; i<40; ++i) s += exp(lp[i]-m);
  double ls = log(s);
  for (int i=0; i<40; ++i) out[(size_t)b*40+i] = (float)(lp[i] - m - ls);
}

// ---------------------------------------------------------------------------
extern "C" void kernel_launch(void* const* d_in, const int* in_sizes, int n_in,
                              void* d_out, int out_size, void* d_ws, size_t ws_size,
                              hipStream_t stream)
{
  if (ws_size < (size_t)WS_NEEDED) return;

  const float* x   = (const float*)d_in[0];
  const float* c1w = (const float*)d_in[1];  const float* c1b = (const float*)d_in[2];
  const float* g1  = (const float*)d_in[3];  const float* b1  = (const float*)d_in[4];
  const float* s1w = (const float*)d_in[5];  const float* s1b = (const float*)d_in[6];
  const float* c2w = (const float*)d_in[7];  const float* c2b = (const float*)d_in[8];
  const float* g2  = (const float*)d_in[9];  const float* b2  = (const float*)d_in[10];
  const float* s2w = (const float*)d_in[11]; const float* s2b = (const float*)d_in[12];
  const float* c3w = (const float*)d_in[13]; const float* c3b = (const float*)d_in[14];
  const float* g3  = (const float*)d_in[15]; const float* b3  = (const float*)d_in[16];
  const float* c4w = (const float*)d_in[17]; const float* c4b = (const float*)d_in[18];
  const float* s4w = (const float*)d_in[19]; const float* s4b = (const float*)d_in[20];
  const float* g4  = (const float*)d_in[21]; const float* b4  = (const float*)d_in[22];
  const float* f1w = (const float*)d_in[23]; const float* f1b = (const float*)d_in[24];
  const float* f2w = (const float*)d_in[25]; const float* f2b = (const float*)d_in[26];

  char* ws = (char*)d_ws;
  double* s1o = (double*)(ws + OFF_S1O);
  double* s2o = (double*)(ws + OFF_S2O);
  double* part= (double*)(ws + OFF_PART);
  double* c4o = (double*)(ws + OFF_C4O);
  double* c2o = (double*)(ws + OFF_C2O);
  double* c3o = (double*)(ws + OFF_C3O);
  double* fsum= (double*)(ws + OFF_FS);
  double* cnt = (double*)(ws + OFF_CNT);
  float*  m20 = (float*)(ws + OFF_M20);
  float*  m10 = (float*)(ws + OFF_M10);
  double* s4o = (double*)(ws + OFF_S4O);
  double* fc1o= (double*)(ws + OFF_FC1);
  double* logd= (double*)(ws + OFF_LOG);

  for (int q = 0; q < 4; ++q){
    int qb0 = q * QB_;

    // ---- stage 1: 2 scatter-chunks of 4 batches -> fused c1/LN1/s1 ----
    for (int sc = 0; sc < QB_/CB_; ++sc){
      int b0  = qb0 + sc*CB_;
      int lb0 = sc*CB_;
      hipMemsetAsync(ws + OFF_FS, 0, (size_t)CB_*24*64000*8 + (size_t)CB_*64000*8, stream);
      encode_scatter<<<cdiv((long)CB_*N_,256),256,0,stream>>>(x, fsum, cnt, b0);
      pool_cnt_m20  <<<cdiv((long)CB_*8000,256),256,0,stream>>>(cnt, m20 + (size_t)b0*8000);
      c1_ln_s1<<<CB_*8000, 64, 0, stream>>>(fsum, cnt, c1w, c1b, g1, b1,
                                            s1w, s1b, s1o, lb0);
    }
    pool_mask_f<<<cdiv((long)QB_*1000,256),256,0,stream>>>(
        m20 + (size_t)qb0*8000, m10 + (size_t)qb0*1000, 10, QB_);

    // ---- stage 2: c2 via fp64 MFMA (32 couts/wave, shared B) + LN2 + s2 ----
    launch_cmf(s1o, c2w, c2b, c2o, 64, 128, 20, QB_, stream);
    ln_chan_d<<<cdiv((long)QB_*8000,256),256,0,stream>>>(
        c2o, g2, b2, m20 + (size_t)qb0*8000, 128, 8000, QB_);
    launch_conv<2,2,0, 2,8, 1,128, true,true,false>(c2o, s2w, s2b,
        m10 + (size_t)qb0*1000, s2o, 128, 20, 256, 10, QB_, 1, stream);

    // ---- stage 3: c3 via fp64 MFMA (32 couts/wave, shared B) + LN3 ----
    launch_cmf(s2o, c3w, c3b, c3o, 256, 512, 10, QB_, stream);
    ln_chan_d<<<cdiv((long)QB_*1000,256),256,0,stream>>>(
        c3o, g3, b3, m10 + (size_t)qb0*1000, 512, 1000, QB_);

    // ---- stage 4: c4 partial (4 Cin-chunks) + reduce(relu) ; s4 ----
    launch_conv<3,2,0, 2,4, 8,8, false,false,true>(c3o, c4w, c4b, nullptr,
        part, 512, 10, 1024, 4, QB_, 4, stream);
    c4_reduce<<<cdiv((long)QB_*1024*64,256),256,0,stream>>>(part, c4b, c4o, QB_, 4);
    s4_wave<<<cdiv((long)QB_*1024*64,256),256,0,stream>>>(
        c4o, s4w, s4b, s4o + (size_t)qb0*8192, QB_);
  }

  // ---- head (fp64) ----
  ln_vec<<<B_,256,0,stream>>>(s4o, g4, b4);
  fc_wave<<<cdiv((long)B_*1024*64,256),256,0,stream>>>(s4o, f1w, f1b, fc1o, 8192, 1024, 1);
  fc_wave<<<cdiv((long)B_*40*64,256),  256,0,stream>>>(fc1o, f2w, f2b, logd, 1024, 40, 0);
  lsm_out<<<1,64,0,stream>>>(logd, (float*)d_out);
}

// Round 24
// 22653.741 us; speedup vs baseline: 1.0407x; 1.0040x over previous
//
#include <hip/hip_runtime.h>
#include <math.h>

#define B_ 32
#define N_ 8192
#define G_ 40
#define CB_ 4                 // batches per scatter chunk (stage-1)
#define QB_ 8                 // batches per quarter (trunk pass)

static inline int cdiv(long a, int b){ return (int)((a + (long)b - 1)/b); }

typedef double d4 __attribute__((ext_vector_type(4)));

// ---------------------------------------------------------------------------
// workspace layout (bytes); peak < 101,768,000 proven safe
// ---------------------------------------------------------------------------
#define OFF_S1O   0            // [8,64,8000]  f64 32,768,000 (stage1 -> c2)
#define OFF_S2O   0            // [8,256,1000] f64 16,384,000 (s1o dead)
#define OFF_PART  0            // [4,8,1024,64] f64 16,777,216 (s2o dead, c4 partials)
#define OFF_C4O   16777216     // [8,1024,64]  f64  4,194,304 ends 20,971,520
#define OFF_FC1   20971520     // [32,1024] f64 262,144 (trunk dead at head)
#define OFF_LOG   21233664     // [32,40]   f64  10,240
#define OFF_C2O   32768000     // [8,128,8000] f64 65,536,000 ends 98,304,000
#define OFF_FS    32768000     //   [4,24,64000] f64 49,152,000 (alias, pre-c2)
#define OFF_CNT   81920000     //   [4,64000] f64 2,048,000 (alias, contiguous w/ FS)
#define OFF_C3O   32768000     // [8,512,1000] f64 32,768,000 (c2o dead)
#define OFF_M20   98304000     // [32,8000] f32 1,024,000
#define OFF_M10   99328000     // [32,1000] f32   128,000
#define OFF_S4O   99456000     // [32,8192] f64 2,097,152 ends 101,553,152
#define WS_NEEDED 101560000

// ---------------------------------------------------------------------------
// 1. encode + scatter (fp32 voxel index math; sin/cos + double-angle recurrence)
// ---------------------------------------------------------------------------
__global__ __launch_bounds__(256) void encode_scatter(const float* __restrict__ x,
    double* __restrict__ fsum, double* __restrict__ cnt, int b0)
{
  int tid = blockIdx.x*256 + threadIdx.x;
  if (tid >= CB_*N_) return;
  int bl = tid / N_;
  const float* p = x + ((size_t)b0*N_ + (size_t)tid)*3;
  float c[3] = { p[0], p[1], p[2] };
  int vi[3];
  #pragma unroll
  for (int ci=0; ci<3; ++ci){
    int v = (int)floorf(c[ci] / 0.05f);
    v = v < -20 ? -20 : (v > 19 ? 19 : v);
    vi[ci] = v + 20;
  }
  int lin = (vi[0]*G_ + vi[1])*G_ + vi[2];
  double* fs = fsum + (size_t)bl*24*64000 + lin;
  const float PI_F = 3.14159265358979323846f;
  #pragma unroll
  for (int ci=0; ci<3; ++ci){
    double ang = (double)c[ci] * (double)PI_F;
    double s = sin(ang), co = cos(ang);
    #pragma unroll
    for (int k=0; k<4; ++k){
      atomicAdd(fs + (size_t)(ci*8 + k)    *64000, s);
      atomicAdd(fs + (size_t)(ci*8 + 4 + k)*64000, co);
      double s2 = 2.0*s*co;
      double c2 = co*co - s*s;
      s = s2; co = c2;
    }
  }
  atomicAdd(cnt + (size_t)bl*64000 + lin, 1.0);
}

// pooled mask 40->20 straight from cnt (f32 out, slice pre-offset)
__global__ __launch_bounds__(256) void pool_cnt_m20(const double* __restrict__ cnt,
    float* __restrict__ m20)
{
  int tid = blockIdx.x*256 + threadIdx.x;
  if (tid >= CB_*8000) return;
  int xo = tid % 20; int t = tid/20;
  int yo = t % 20;   t /= 20;
  int zo = t % 20;   int bl = t/20;
  const double* cb = cnt + (size_t)bl*64000;
  float mx = 0.0f;
  for (int dz=0; dz<2; ++dz)
    for (int dy=0; dy<2; ++dy)
      for (int dx=0; dx<2; ++dx)
        if (cb[(size_t)((zo*2+dz)*40 + (yo*2+dy))*40 + (xo*2+dx)] > 0.0) mx = 1.0f;
  m20[(size_t)bl*8000 + (zo*20+yo)*20+xo] = mx;
}

// mask maxpool 2x2x2 f32
__global__ __launch_bounds__(256) void pool_mask_f(const float* __restrict__ m,
    float* __restrict__ mo, int Do, int NB)
{
  long tid = (long)blockIdx.x*256 + threadIdx.x;
  if (tid >= (long)NB*Do*Do*Do) return;
  int Di = Do*2;
  int xo = (int)(tid % Do); long t = tid / Do;
  int yo = (int)(t % Do);   t /= Do;
  int zo = (int)(t % Do);   int b = (int)(t / Do);
  const float* mb = m + (size_t)b*Di*Di*Di;
  float mx = 0.0f;
  for (int dz=0; dz<2; ++dz)
    for (int dy=0; dy<2; ++dy)
      for (int dx=0; dx<2; ++dx)
        mx = fmaxf(mx, mb[(size_t)(zo*2+dz)*Di*Di + (size_t)(yo*2+dy)*Di + (xo*2+dx)]);
  mo[tid] = mx;
}

// ---------------------------------------------------------------------------
// 2. FUSED c1 + LN1 + s1 (r8-audited; fp64 out). One wave per s1 voxel.
// ---------------------------------------------------------------------------
__global__ __launch_bounds__(64) void c1_ln_s1(
    const double* __restrict__ fsum, const double* __restrict__ cnt,
    const float* __restrict__ c1w, const float* __restrict__ c1b,
    const float* __restrict__ g1,  const float* __restrict__ b1,
    const float* __restrict__ s1w, const float* __restrict__ s1b,
    double* __restrict__ out, int lb0)             // out: s1o quarter [8,64,8000]
{
  __shared__ double sfeat[24][64];
  __shared__ double sh1[32][8];
  __shared__ double smask[8];

  int blk = blockIdx.x;
  int xo = blk % 20; int t1 = blk/20;
  int yo = t1 % 20;  t1 /= 20;
  int zo = t1 % 20;  int bl = t1/20;
  int t = threadIdx.x;

  int lz = t >> 4, ly = (t >> 2) & 3, lx = t & 3;
  int gz = zo*2 - 1 + lz, gy = yo*2 - 1 + ly, gx = xo*2 - 1 + lx;
  bool inb = (gz>=0 && gz<40) && (gy>=0 && gy<40) && (gx>=0 && gx<40);
  int vox = (gz*40 + gy)*40 + gx;
  double cv = inb ? cnt[(size_t)bl*64000 + vox] : 0.0;
  double ic = (cv > 0.0) ? 1.0/cv : 0.0;
  const double* fb = fsum + (size_t)bl*24*64000 + (inb ? vox : 0);
  #pragma unroll
  for (int ci=0; ci<24; ++ci)
    sfeat[ci][t] = ic * fb[(size_t)ci*64000];
  if (t < 8){
    int dz=t>>2, dy=(t>>1)&1, dx=t&1;
    double c8 = cnt[(size_t)bl*64000 + (size_t)((zo*2+dz)*40 + (yo*2+dy))*40 + (xo*2+dx)];
    smask[t] = (c8 > 0.0) ? 1.0 : 0.0;
  }
  __syncthreads();

  double pm = fmax(fmax(fmax(smask[0],smask[1]),fmax(smask[2],smask[3])),
                   fmax(fmax(smask[4],smask[5]),fmax(smask[6],smask[7])));
  int ovox = (zo*20 + yo)*20 + xo;
  double* ob = out + (size_t)(lb0+bl)*64*8000 + ovox;
  if (pm == 0.0){
    ob[(size_t)t*8000] = 0.0;
    return;
  }

  int c   = t & 31;
  int svh = t >> 5;
  double acc[4] = {0,0,0,0};
  const float* wc = c1w + (size_t)c*24*27;
  for (int ci=0; ci<24; ++ci){
    const float* wp = wc + ci*27;
    const double* sp = &sfeat[ci][0] + svh*16;
    #pragma unroll
    for (int kz=0; kz<3; ++kz)
    #pragma unroll
    for (int ky=0; ky<3; ++ky)
    #pragma unroll
    for (int kx=0; kx<3; ++kx){
      double wv = (double)wp[(kz*3+ky)*3+kx];
      const double* q = sp + kz*16 + ky*4 + kx;
      acc[0] += wv * q[0];
      acc[1] += wv * q[1];
      acc[2] += wv * q[4];
      acc[3] += wv * q[5];
    }
  }
  double bias = (double)c1b[c], gc = (double)g1[c], bc = (double)b1[c];
  double h[4], rs1[4], rs2[4];
  #pragma unroll
  for (int i=0;i<4;++i){
    h[i] = (acc[i] + bias) * smask[svh*4+i];
    rs1[i] = h[i]; rs2[i] = h[i]*h[i];
  }
  #pragma unroll
  for (int off=1; off<32; off<<=1){
    #pragma unroll
    for (int i=0;i<4;++i){
      rs1[i] += __shfl_xor(rs1[i], off);
      rs2[i] += __shfl_xor(rs2[i], off);
    }
  }
  #pragma unroll
  for (int i=0;i<4;++i){
    double mu  = rs1[i]*(1.0/32.0);
    double var = fmax(rs2[i]*(1.0/32.0) - mu*mu, 0.0);
    double r   = 1.0/sqrt(var + 1e-5);
    double yv  = ((h[i]-mu)*r*gc + bc) * smask[svh*4+i];
    sh1[c][svh*4+i] = fmax(yv, 0.0);
  }
  __syncthreads();

  const float* wo = s1w + (size_t)t*256;
  double s = 0.0;
  #pragma unroll
  for (int ci=0; ci<32; ++ci){
    #pragma unroll
    for (int sv=0; sv<8; ++sv)
      s += (double)wo[ci*8+sv] * sh1[ci][sv];
  }
  ob[(size_t)t*8000] = fmax(s + (double)s1b[t], 0.0);
}

// ---------------------------------------------------------------------------
// 3a. MFMA conv, global-B variant (c2; r21-verified). 32 couts/wave, shared B.
// ---------------------------------------------------------------------------
__device__ __forceinline__ double Pf_(int i,int k){ return (double)(1 + i + 31*k); }
__device__ __forceinline__ double Qf_(int k,int j){ return (double)(2 + 3*j + 7*k); }
__device__ __forceinline__ double Rf_(int m,int n){
  double s = 0.0;
  for (int k=0;k<4;++k) s += Pf_(m,k)*Qf_(k,n);
  return s;
}

template<int TI>
__global__ __launch_bounds__(256) void conv_mfma(
    const double* __restrict__ in, const float* __restrict__ w,
    const float* __restrict__ bias, double* __restrict__ out,
    int NB, int Cin, int Cout, int D)
{
  __shared__ float wl[TI*32*27];        // [cc][io(32)][tap]
  int spat = D*D*D;
  const int BV = 64;                    // 4 waves x 16 voxels
  int nvt = (spat + BV - 1) / BV;
  int bid = blockIdx.x;
  int vt4 = bid % nvt; int t1 = bid / nvt;
  int cot = t1 % (Cout/32); int b = t1 / (Cout/32);
  int wid = threadIdx.x >> 6;
  int lane = threadIdx.x & 63;
  int li = lane & 15, lk = lane >> 4;

  d4 z = {0.0,0.0,0.0,0.0};
  d4 det = __builtin_amdgcn_mfma_f64_16x16x4f64(Pf_(li,lk), Qf_(lk,li), z, 0,0,0);
  bool m2 = true, m3 = true;
  #pragma unroll
  for (int r=0;r<4;++r){
    m2 = m2 && (fabs(det[r] - Rf_(lk+4*r, li)) < 1e-3);   // D[lk+4r][li]
    m3 = m3 && (fabs(det[r] - Rf_(li, 4*lk+r)) < 1e-3);   // D[li][4lk+r]
  }
  int mode = __all(m2) ? 2 : (__all(m3) ? 3 : 1);

  int vbase = vt4*BV + wid*16;
  int vox = vbase + li;
  bool vok = vox < spat;
  int vc = vok ? vox : 0;
  int vz = vc/(D*D), vy = (vc/D)%D, vx = vc%D;

  const double* inb = in + (size_t)b*Cin*spat;
  d4 acc0 = {0.0,0.0,0.0,0.0};
  d4 acc1 = {0.0,0.0,0.0,0.0};

  for (int ci0 = 0; ci0 < Cin; ci0 += TI){
    for (int idx = threadIdx.x; idx < TI*32*27; idx += 256){
      int tap = idx % 27; int t2 = idx / 27;
      int io = t2 % 32; int cc = t2 / 32;
      wl[(cc*32 + io)*27 + tap] =
          w[((size_t)(cot*32+io)*Cin + (ci0+cc))*27 + tap];
    }
    __syncthreads();
    const double* ipk = inb + (size_t)(ci0 + lk)*spat;
    #pragma unroll
    for (int dz = 0; dz < 3; ++dz){
      #pragma unroll
      for (int dy = 0; dy < 3; ++dy){
        #pragma unroll
        for (int dx = 0; dx < 3; ++dx){
          int tap = (dz*3+dy)*3+dx;
          int zi = vz+dz-1, yi = vy+dy-1, xi = vx+dx-1;
          bool ok = vok && zi>=0 && zi<D && yi>=0 && yi<D && xi>=0 && xi<D;
          int so = ok ? (zi*D + yi)*D + xi : 0;
          #pragma unroll
          for (int kq = 0; kq < TI/4; ++kq){
            double bv = ok ? ipk[(size_t)(kq*4)*spat + so] : 0.0;
            double a0 = (double)wl[((kq*4+lk)*32 + li)*27 + tap];       // A[co li]
            double a1 = (double)wl[((kq*4+lk)*32 + 16 + li)*27 + tap];  // A[co 16+li]
            acc0 = __builtin_amdgcn_mfma_f64_16x16x4f64(a0, bv, acc0, 0, 0, 0);
            acc1 = __builtin_amdgcn_mfma_f64_16x16x4f64(a1, bv, acc1, 0, 0, 0);
          }
        }
      }
    }
    __syncthreads();
  }

  size_t obb = (size_t)b*Cout*spat;
  if (mode == 2){
    if (vok){
      #pragma unroll
      for (int r = 0; r < 4; ++r){
        int co0 = cot*32 + lk + 4*r;                 // D[lk+4r][li]
        int co1 = co0 + 16;
        out[obb + (size_t)co0*spat + vox] = acc0[r] + (double)bias[co0];
        out[obb + (size_t)co1*spat + vox] = acc1[r] + (double)bias[co1];
      }
    }
  } else if (mode == 3){
    int co0 = cot*32 + li;                           // D[li][4lk+r]
    int co1 = co0 + 16;
    double bv0 = (double)bias[co0], bv1 = (double)bias[co1];
    #pragma unroll
    for (int r = 0; r < 4; ++r){
      int vw = vbase + 4*lk + r;
      if (vw < spat){
        out[obb + (size_t)co0*spat + vw] = acc0[r] + bv0;
        out[obb + (size_t)co1*spat + vw] = acc1[r] + bv1;
      }
    }
  } else {
    if (vok){
      #pragma unroll
      for (int r = 0; r < 4; ++r){
        int co0 = cot*32 + 4*lk + r;                 // fallback
        int co1 = co0 + 16;
        out[obb + (size_t)co0*spat + vox] = acc0[r] + (double)bias[co0];
        out[obb + (size_t)co1*spat + vox] = acc1[r] + (double)bias[co1];
      }
    }
  }
}

static void launch_cmf(const double* in, const float* w, const float* bias,
                       double* out, int Cin, int Cout, int D, int NB, hipStream_t st)
{
  int spat = D*D*D;
  int nvt = (spat + 63)/64;
  int grid = NB * (Cout/32) * nvt;
  conv_mfma<8><<<grid,256,0,st>>>(in, w, bias, out, NB, Cin, Cout, D);
}

// ---------------------------------------------------------------------------
// 3b. MFMA conv, LDS-staged-B variant (c3, D=10). Block = 64 linear voxels;
//     all 27 tap offsets are linear shifts in [-111,+111] so the B working
//     set per ci-stage is sIn[8][286]. Same mfma core / writeout as 3a.
// ---------------------------------------------------------------------------
__global__ __launch_bounds__(256) void conv_mfma_l(
    const double* __restrict__ in, const float* __restrict__ w,
    const float* __restrict__ bias, double* __restrict__ out,
    int NB, int Cin, int Cout)
{
  const int D = 10, spat = 1000;
  const int TI = 8, HALO = 111, WIN = 64 + 2*HALO;   // 286
  __shared__ float  wl[TI*32*27];                    // 27,648 B
  __shared__ double sIn[TI][WIN];                    // 18,304 B

  const int BV = 64;
  int nvt = (spat + BV - 1) / BV;                    // 16
  int bid = blockIdx.x;
  int vt4 = bid % nvt; int t1 = bid / nvt;
  int cot = t1 % (Cout/32); int b = t1 / (Cout/32);
  int wid = threadIdx.x >> 6;
  int lane = threadIdx.x & 63;
  int li = lane & 15, lk = lane >> 4;

  d4 z = {0.0,0.0,0.0,0.0};
  d4 det = __builtin_amdgcn_mfma_f64_16x16x4f64(Pf_(li,lk), Qf_(lk,li), z, 0,0,0);
  bool m2 = true, m3 = true;
  #pragma unroll
  for (int r=0;r<4;++r){
    m2 = m2 && (fabs(det[r] - Rf_(lk+4*r, li)) < 1e-3);
    m3 = m3 && (fabs(det[r] - Rf_(li, 4*lk+r)) < 1e-3);
  }
  int mode = __all(m2) ? 2 : (__all(m3) ? 3 : 1);

  int blk0 = vt4*BV;                                 // block's first voxel
  int vbase = blk0 + wid*16;
  int vox = vbase + li;
  bool vok = vox < spat;
  int vc = vok ? vox : 0;
  int vz = vc/(D*D), vy = (vc/D)%D, vx = vc%D;
  int rel_base = wid*16 + li + HALO;                 // in [111, 174]

  const double* inb = in + (size_t)b*Cin*spat;
  d4 acc0 = {0.0,0.0,0.0,0.0};
  d4 acc1 = {0.0,0.0,0.0,0.0};

  for (int ci0 = 0; ci0 < Cin; ci0 += TI){
    // stage weights [cc][io][tap]
    for (int idx = threadIdx.x; idx < TI*32*27; idx += 256){
      int tap = idx % 27; int t2 = idx / 27;
      int io = t2 % 32; int cc = t2 / 32;
      wl[(cc*32 + io)*27 + tap] =
          w[((size_t)(cot*32+io)*Cin + (ci0+cc))*27 + tap];
    }
    // stage input window [cin][rel]: global [blk0-HALO, blk0+63+HALO], clamped
    for (int idx = threadIdx.x; idx < TI*WIN; idx += 256){
      int rel = idx % WIN; int cin = idx / WIN;
      int g = blk0 - HALO + rel;
      g = g < 0 ? 0 : (g >= spat ? spat-1 : g);
      sIn[cin][rel] = inb[(size_t)(ci0+cin)*spat + g];
    }
    __syncthreads();
    #pragma unroll
    for (int dz = 0; dz < 3; ++dz){
      #pragma unroll
      for (int dy = 0; dy < 3; ++dy){
        #pragma unroll
        for (int dx = 0; dx < 3; ++dx){
          int tap = (dz*3+dy)*3+dx;
          int off = (dz-1)*100 + (dy-1)*10 + (dx-1);  // linear shift
          int zi = vz+dz-1, yi = vy+dy-1, xi = vx+dx-1;
          bool ok = vok && zi>=0 && zi<D && yi>=0 && yi<D && xi>=0 && xi<D;
          int rel = rel_base + off;                   // in [0, 285]
          #pragma unroll
          for (int kq = 0; kq < TI/4; ++kq){
            double bv = ok ? sIn[kq*4+lk][rel] : 0.0;
            double a0 = (double)wl[((kq*4+lk)*32 + li)*27 + tap];
            double a1 = (double)wl[((kq*4+lk)*32 + 16 + li)*27 + tap];
            acc0 = __builtin_amdgcn_mfma_f64_16x16x4f64(a0, bv, acc0, 0, 0, 0);
            acc1 = __builtin_amdgcn_mfma_f64_16x16x4f64(a1, bv, acc1, 0, 0, 0);
          }
        }
      }
    }
    __syncthreads();
  }

  size_t obb = (size_t)b*Cout*spat;
  if (mode == 2){
    if (vok){
      #pragma unroll
      for (int r = 0; r < 4; ++r){
        int co0 = cot*32 + lk + 4*r;
        int co1 = co0 + 16;
        out[obb + (size_t)co0*spat + vox] = acc0[r] + (double)bias[co0];
        out[obb + (size_t)co1*spat + vox] = acc1[r] + (double)bias[co1];
      }
    }
  } else if (mode == 3){
    int co0 = cot*32 + li;
    int co1 = co0 + 16;
    double bv0 = (double)bias[co0], bv1 = (double)bias[co1];
    #pragma unroll
    for (int r = 0; r < 4; ++r){
      int vw = vbase + 4*lk + r;
      if (vw < spat){
        out[obb + (size_t)co0*spat + vw] = acc0[r] + bv0;
        out[obb + (size_t)co1*spat + vw] = acc1[r] + bv1;
      }
    }
  } else {
    if (vok){
      #pragma unroll
      for (int r = 0; r < 4; ++r){
        int co0 = cot*32 + 4*lk + r;
        int co1 = co0 + 16;
        out[obb + (size_t)co0*spat + vox] = acc0[r] + (double)bias[co0];
        out[obb + (size_t)co1*spat + vox] = acc1[r] + (double)bias[co1];
      }
    }
  }
}

static void launch_cmf_l(const double* in, const float* w, const float* bias,
                         double* out, int Cin, int Cout, int NB, hipStream_t st)
{
  int nvt = (1000 + 63)/64;
  int grid = NB * (Cout/32) * nvt;
  conv_mfma_l<<<grid,256,0,st>>>(in, w, bias, out, NB, Cin, Cout);
}

// ---------------------------------------------------------------------------
// 4. conv3d, LDS-staged f32 weights, fp64 VALU math (s2, c4)
// ---------------------------------------------------------------------------
template<int K, int S, int P, int XT, int CT, int CGB, int TI,
         bool MMUL, bool RELU_, bool PARTIAL>
__global__ __launch_bounds__(256) void conv_lds(
    const double* __restrict__ in, const float* __restrict__ w,
    const float* __restrict__ bias, const float* __restrict__ mask,
    double* __restrict__ out, int NB, int Cin, int Din, int Cout, int Dout,
    int ncic, int cich)
{
  const int K3 = K*K*K;
  const int SP = 256/CGB;
  const int NR = (XT-1)*S + K;
  __shared__ float wl[CGB*CT][TI*K3];

  int tilesx = (Dout + XT - 1)/XT;
  int spat = tilesx*Dout*Dout;
  int nsb = (spat + SP - 1)/SP;
  int bid = blockIdx.x;
  int cic = 0;
  if (PARTIAL){ cic = bid % ncic; bid /= ncic; }
  int sb = bid % nsb;  int t1 = bid / nsb;
  int ncgo = Cout/(CT*CGB);
  int cgo = t1 % ncgo; int b = t1 / ncgo;
  int ciBeg = PARTIAL ? cic*cich : 0;
  int ciEnd = PARTIAL ? ciBeg + cich : Cin;

  int lc = threadIdx.x / SP;
  int sp = threadIdx.x % SP;
  int sidx = sb*SP + sp;
  bool act = sidx < spat;
  int sc = act ? sidx : 0;
  int tx = sc % tilesx;
  int y  = (sc/tilesx) % Dout;
  int z  = sc/(tilesx*Dout);
  int x0 = tx*XT;
  int co0 = (cgo*CGB + lc)*CT;

  int DD = Din*Din;
  const double* inb = in + (size_t)b*Cin*Din*DD;
  const int wcs = Cin*K3;

  double acc[CT][XT];
  #pragma unroll
  for (int c=0;c<CT;++c){
    double bv = PARTIAL ? 0.0 : (double)bias[co0+c];
    #pragma unroll
    for (int i=0;i<XT;++i) acc[c][i]=bv;
  }

  for (int ci0=ciBeg; ci0<ciEnd; ci0+=TI){
    const int cnt_w = CGB*CT*TI*K3;
    for (int idx = threadIdx.x; idx < cnt_w; idx += 256){
      int k  = idx % K3; int t2 = idx / K3;
      int cil= t2 % TI;  int cr = t2 / TI;
      int co = cgo*CGB*CT + cr;
      float v = 0.0f;
      if (ci0+cil < ciEnd) v = w[(size_t)co*wcs + (size_t)(ci0+cil)*K3 + k];
      wl[cr][cil*K3 + k] = v;
    }
    __syncthreads();
    int tmax = min(TI, ciEnd-ci0);
    for (int cil=0; cil<tmax; ++cil){
      const double* inc = inb + (size_t)(ci0+cil)*Din*DD;
      #pragma unroll
      for (int dz=0; dz<K; ++dz){
        int zi = z*S + dz - P;
        if (zi < 0 || zi >= Din) continue;
        #pragma unroll
        for (int dy=0; dy<K; ++dy){
          int yi = y*S + dy - P;
          if (yi < 0 || yi >= Din) continue;
          const double* row = inc + (size_t)zi*DD + (size_t)yi*Din;
          double rv[NR];
          #pragma unroll
          for (int r=0;r<NR;++r){
            int xi = x0*S + r - P;
            rv[r] = (xi>=0 && xi<Din) ? row[xi] : 0.0;
          }
          #pragma unroll
          for (int dx=0; dx<K; ++dx){
            double wv[CT];
            #pragma unroll
            for (int c=0;c<CT;++c)
              wv[c] = (double)wl[lc*CT+c][cil*K3 + (dz*K+dy)*K + dx];
            #pragma unroll
            for (int i=0;i<XT;++i)
              #pragma unroll
              for (int c=0;c<CT;++c) acc[c][i] += wv[c]*rv[i*S+dx];
          }
        }
      }
    }
    __syncthreads();
  }

  if (act){
    int oDD = Dout*Dout;
    size_t chunk_off = PARTIAL ? (size_t)cic*NB*Cout*Dout*oDD : 0;
    size_t ob = chunk_off + (size_t)b*Cout*Dout*oDD + (size_t)z*oDD + (size_t)y*Dout;
    #pragma unroll
    for (int i=0;i<XT;++i){
      int xo = x0+i;
      if (xo >= Dout) continue;
      double mv = 1.0;
      if (MMUL) mv = (double)mask[(size_t)b*Dout*oDD + (size_t)z*oDD + (size_t)y*Dout + xo];
      #pragma unroll
      for (int c=0;c<CT;++c){
        double v = acc[c][i];
        if (MMUL) v *= mv;
        if (RELU_) v = fmax(v,0.0);
        out[ob + (size_t)(co0+c)*Dout*oDD + xo] = v;
      }
    }
  }
}

template<int K,int S,int P,int XT,int CT,int CGB,int TI,bool MM,bool RL,bool PART>
static void launch_conv(const double* in, const float* w, const float* bias,
                        const float* mask, double* out,
                        int Cin, int Din, int Cout, int Dout, int NB,
                        int ncic, hipStream_t st)
{
  const int SP = 256/CGB;
  int tilesx = (Dout+XT-1)/XT;
  int spat = tilesx*Dout*Dout;
  int nsb = (spat + SP - 1)/SP;
  long grid = (long)(PART?ncic:1) * NB * (Cout/(CT*CGB)) * nsb;
  conv_lds<K,S,P,XT,CT,CGB,TI,MM,RL,PART><<<(int)grid,256,0,st>>>(
      in,w,bias,mask,out,NB,Cin,Din,Cout,Dout,ncic,Cin/(PART?ncic:1));
}

// sum NCIC c4 partials + bias + relu -> c4o
__global__ __launch_bounds__(256) void c4_reduce(const double* __restrict__ part,
    const float* __restrict__ bias, double* __restrict__ out, int NB, int ncic)
{
  long tid = (long)blockIdx.x*256 + threadIdx.x;
  long total = (long)NB*1024*64;
  if (tid >= total) return;
  int co = (int)((tid >> 6) & 1023);
  double s = (double)bias[co];
  for (int c=0; c<ncic; ++c) s += part[(size_t)c*total + tid];
  out[tid] = fmax(s, 0.0);
}

// ---------------------------------------------------------------------------
// 5. s4: one wave per (b,co), 8 outputs
// ---------------------------------------------------------------------------
__global__ __launch_bounds__(256) void s4_wave(const double* __restrict__ c4o,
    const float* __restrict__ w, const float* __restrict__ bias,
    double* __restrict__ out, int NB)
{
  long gt = (long)blockIdx.x*256 + threadIdx.x;
  int wid = (int)(gt >> 6);
  int lane = threadIdx.x & 63;
  if (wid >= NB*1024) return;
  int co = wid & 1023; int b = wid >> 10;
  const double* ib = c4o + (size_t)b*1024*64;
  const float* wp = w + (size_t)co*8192;
  double acc[8] = {0,0,0,0,0,0,0,0};
  for (int k=lane; k<8192; k+=64){
    double wv = (double)wp[k];
    int ci = k>>3, sv = k&7;
    int dz = sv>>2, dy=(sv>>1)&1, dx=sv&1;
    const double* icp = ib + (size_t)ci*64;
    #pragma unroll
    for (int v=0; v<8; ++v){
      int zo=v>>2, yo=(v>>1)&1, xo=v&1;
      acc[v] += wv * icp[((zo*2+dz)*4+(yo*2+dy))*4 + (xo*2+dx)];
    }
  }
  #pragma unroll
  for (int v=0;v<8;++v){
    double a = acc[v];
    #pragma unroll
    for (int off=32;off>0;off>>=1) a += __shfl_down(a, off);
    if (lane==0) out[((size_t)b*1024+co)*8 + v] = a + (double)bias[co];
  }
}

// ---------------------------------------------------------------------------
// 6. channel LayerNorm: fp64 x, f32 params/mask, two-pass (applies mask)
// ---------------------------------------------------------------------------
__global__ __launch_bounds__(256) void ln_chan_d(double* __restrict__ x,
    const float* __restrict__ g, const float* __restrict__ bt,
    const float* __restrict__ mask, int C, int V, int NB)
{
  long tid = (long)blockIdx.x*256 + threadIdx.x;
  if (tid >= (long)NB*V) return;
  int b = (int)(tid / V);
  int v = (int)(tid - (long)b*V);
  double* xp = x + (size_t)b*C*V + v;
  double s = 0.0;
  for (int c=0; c<C; ++c) s += xp[(size_t)c*V];
  double mu = s / C;
  double s2 = 0.0;
  for (int c=0; c<C; ++c){ double d = xp[(size_t)c*V] - mu; s2 += d*d; }
  double r  = 1.0/sqrt(s2 / C + 1e-5);
  double mv = (double)mask[tid];
  for (int c=0; c<C; ++c){
    double yv = ((xp[(size_t)c*V] - mu) * r * (double)g[c] + (double)bt[c]) * mv;
    xp[(size_t)c*V] = fmax(yv, 0.0);
  }
}

// ---------------------------------------------------------------------------
// 7. head — fp64
// ---------------------------------------------------------------------------
__global__ __launch_bounds__(256) void ln_vec(double* __restrict__ h,
    const float* __restrict__ g, const float* __restrict__ bt)
{
  __shared__ double red[256];
  int b = blockIdx.x, t = threadIdx.x;
  double* hp = h + (size_t)b*8192;
  double s = 0.0;
  for (int k=t; k<8192; k+=256) s += hp[k];
  red[t] = s; __syncthreads();
  for (int o=128; o>0; o>>=1){ if (t<o) red[t] += red[t+o]; __syncthreads(); }
  double mu = red[0] / 8192.0;  __syncthreads();
  double s2 = 0.0;
  for (int k=t; k<8192; k+=256){ double d = hp[k]-mu; s2 += d*d; }
  red[t] = s2; __syncthreads();
  for (int o=128; o>0; o>>=1){ if (t<o) red[t] += red[t+o]; __syncthreads(); }
  double r = 1.0/sqrt(red[0]/8192.0 + 1e-5);
  for (int k=t; k<8192; k+=256)
    hp[k] = fmax((hp[k]-mu)*r*(double)g[k] + (double)bt[k], 0.0);
}

__global__ __launch_bounds__(256) void fc_wave(const double* __restrict__ h,
    const float* __restrict__ w, const float* __restrict__ bias,
    double* __restrict__ out, int Kdim, int O, int relu)
{
  long gt = (long)blockIdx.x*256 + threadIdx.x;
  int wid  = (int)(gt >> 6);
  int lane = threadIdx.x & 63;
  if (wid >= B_*O) return;
  int b = wid / O, o = wid - b*O;
  const double* hp = h + (size_t)b*Kdim;
  const float*  wp = w + (size_t)o*Kdim;
  double acc = 0.0;
  for (int k=lane; k<Kdim; k+=64) acc += hp[k]*(double)wp[k];
  #pragma unroll
  for (int off=32; off>0; off>>=1) acc += __shfl_down(acc, off);
  if (lane == 0){
    double v = acc + (double)bias[o];
    if (relu) v = fmax(v, 0.0);
    out[(size_t)b*O + o] = v;
  }
}

__global__ __launch_bounds__(64) void lsm_out(const double* __restrict__ logits,
    float* __restrict__ out)
{
  int b = threadIdx.x;
  if (b >= B_) return;
  const double* lp = logits + (size_t)b*40;
  double m = lp[0];
  for (int i=1; i<40; ++i) m = lp[i] > m ? lp[i] : m;
  double s = 0.0;
  for (int i=0; i<40; ++i) s += exp(lp[i]-m);
  double ls = log(s);
  for (int i=0; i<40; ++i) out[(size_t)b*40+i] = (float)(lp[i] - m - ls);
}

// ---------------------------------------------------------------------------
extern "C" void kernel_launch(void* const* d_in, const int* in_sizes, int n_in,
                              void* d_out, int out_size, void* d_ws, size_t ws_size,
                              hipStream_t stream)
{
  if (ws_size < (size_t)WS_NEEDED) return;

  const float* x   = (const float*)d_in[0];
  const float* c1w = (const float*)d_in[1];  const float* c1b = (const float*)d_in[2];
  const float* g1  = (const float*)d_in[3];  const float* b1  = (const float*)d_in[4];
  const float* s1w = (const float*)d_in[5];  const float* s1b = (const float*)d_in[6];
  const float* c2w = (const float*)d_in[7];  const float* c2b = (const float*)d_in[8];
  const float* g2  = (const float*)d_in[9];  const float* b2  = (const float*)d_in[10];
  const float* s2w = (const float*)d_in[11]; const float* s2b = (const float*)d_in[12];
  const float* c3w = (const float*)d_in[13]; const float* c3b = (const float*)d_in[14];
  const float* g3  = (const float*)d_in[15]; const float* b3  = (const float*)d_in[16];
  const float* c4w = (const float*)d_in[17]; const float* c4b = (const float*)d_in[18];
  const float* s4w = (const float*)d_in[19]; const float* s4b = (const float*)d_in[20];
  const float* g4  = (const float*)d_in[21]; const float* b4  = (const float*)d_in[22];
  const float* f1w = (const float*)d_in[23]; const float* f1b = (const float*)d_in[24];
  const float* f2w = (const float*)d_in[25]; const float* f2b = (const float*)d_in[26];

  char* ws = (char*)d_ws;
  double* s1o = (double*)(ws + OFF_S1O);
  double* s2o = (double*)(ws + OFF_S2O);
  double* part= (double*)(ws + OFF_PART);
  double* c4o = (double*)(ws + OFF_C4O);
  double* c2o = (double*)(ws + OFF_C2O);
  double* c3o = (double*)(ws + OFF_C3O);
  double* fsum= (double*)(ws + OFF_FS);
  double* cnt = (double*)(ws + OFF_CNT);
  float*  m20 = (float*)(ws + OFF_M20);
  float*  m10 = (float*)(ws + OFF_M10);
  double* s4o = (double*)(ws + OFF_S4O);
  double* fc1o= (double*)(ws + OFF_FC1);
  double* logd= (double*)(ws + OFF_LOG);

  for (int q = 0; q < 4; ++q){
    int qb0 = q * QB_;

    // ---- stage 1: 2 scatter-chunks of 4 batches -> fused c1/LN1/s1 ----
    for (int sc = 0; sc < QB_/CB_; ++sc){
      int b0  = qb0 + sc*CB_;
      int lb0 = sc*CB_;
      hipMemsetAsync(ws + OFF_FS, 0, (size_t)CB_*24*64000*8 + (size_t)CB_*64000*8, stream);
      encode_scatter<<<cdiv((long)CB_*N_,256),256,0,stream>>>(x, fsum, cnt, b0);
      pool_cnt_m20  <<<cdiv((long)CB_*8000,256),256,0,stream>>>(cnt, m20 + (size_t)b0*8000);
      c1_ln_s1<<<CB_*8000, 64, 0, stream>>>(fsum, cnt, c1w, c1b, g1, b1,
                                            s1w, s1b, s1o, lb0);
    }
    pool_mask_f<<<cdiv((long)QB_*1000,256),256,0,stream>>>(
        m20 + (size_t)qb0*8000, m10 + (size_t)qb0*1000, 10, QB_);

    // ---- stage 2: c2 via fp64 MFMA (global-B) + LN2 + s2 ----
    launch_cmf(s1o, c2w, c2b, c2o, 64, 128, 20, QB_, stream);
    ln_chan_d<<<cdiv((long)QB_*8000,256),256,0,stream>>>(
        c2o, g2, b2, m20 + (size_t)qb0*8000, 128, 8000, QB_);
    launch_conv<2,2,0, 2,8, 1,128, true,true,false>(c2o, s2w, s2b,
        m10 + (size_t)qb0*1000, s2o, 128, 20, 256, 10, QB_, 1, stream);

    // ---- stage 3: c3 via fp64 MFMA (LDS-staged B) + LN3 ----
    launch_cmf_l(s2o, c3w, c3b, c3o, 256, 512, QB_, stream);
    ln_chan_d<<<cdiv((long)QB_*1000,256),256,0,stream>>>(
        c3o, g3, b3, m10 + (size_t)qb0*1000, 512, 1000, QB_);

    // ---- stage 4: c4 partial (4 Cin-chunks) + reduce(relu) ; s4 ----
    launch_conv<3,2,0, 2,4, 8,8, false,false,true>(c3o, c4w, c4b, nullptr,
        part, 512, 10, 1024, 4, QB_, 4, stream);
    c4_reduce<<<cdiv((long)QB_*1024*64,256),256,0,stream>>>(part, c4b, c4o, QB_, 4);
    s4_wave<<<cdiv((long)QB_*1024*64,256),256,0,stream>>>(
        c4o, s4w, s4b, s4o + (size_t)qb0*8192, QB_);
  }

  // ---- head (fp64) ----
  ln_vec<<<B_,256,0,stream>>>(s4o, g4, b4);
  fc_wave<<<cdiv((long)B_*1024*64,256),256,0,stream>>>(s4o, f1w, f1b, fc1o, 8192, 1024, 1);
  fc_wave<<<cdiv((long)B_*40*64,256),  256,0,stream>>>(fc1o, f2w, f2b, logd, 1024, 40, 0);
  lsm_out<<<1,64,0,stream>>>(logd, (float*)d_out);
}

// Round 25
// 21940.927 us; speedup vs baseline: 1.0745x; 1.0325x over previous
//
#include <hip/hip_runtime.h>
#include <math.h>

#define B_ 32
#define N_ 8192
#define G_ 40
#define CB_ 4                 // batches per scatter chunk (stage-1)
#define QB_ 8                 // batches per quarter (trunk pass)

static inline int cdiv(long a, int b){ return (int)((a + (long)b - 1)/b); }

typedef double d4 __attribute__((ext_vector_type(4)));

// ---------------------------------------------------------------------------
// workspace layout (bytes); peak < 101,768,000 proven safe
// ---------------------------------------------------------------------------
#define OFF_S1O   0            // [8,64,8000]  f64 32,768,000 (stage1 -> c2)
#define OFF_S2O   0            // [8,256,1000] f64 16,384,000 (s1o dead)
#define OFF_PART  0            // [4,8,1024,64] f64 16,777,216 (s2o dead, c4 partials)
#define OFF_C4O   16777216     // [8,1024,64]  f64  4,194,304 ends 20,971,520
#define OFF_FC1   20971520     // [32,1024] f64 262,144 (trunk dead at head)
#define OFF_LOG   21233664     // [32,40]   f64  10,240
#define OFF_C2O   32768000     // [8,128,8000] f64 65,536,000 ends 98,304,000
#define OFF_FS    32768000     //   [4,24,64000] f64 49,152,000 (alias, pre-c2)
#define OFF_CNT   81920000     //   [4,64000] f64 2,048,000 (alias, contiguous w/ FS)
#define OFF_C3O   32768000     // [8,512,1000] f64 32,768,000 (c2o dead)
#define OFF_M20   98304000     // [32,8000] f32 1,024,000
#define OFF_M10   99328000     // [32,1000] f32   128,000
#define OFF_S4O   99456000     // [32,8192] f64 2,097,152 ends 101,553,152
#define WS_NEEDED 101560000

// ---------------------------------------------------------------------------
// 1. encode + scatter (fp32 voxel index math; sin/cos + double-angle recurrence)
// ---------------------------------------------------------------------------
__global__ __launch_bounds__(256) void encode_scatter(const float* __restrict__ x,
    double* __restrict__ fsum, double* __restrict__ cnt, int b0)
{
  int tid = blockIdx.x*256 + threadIdx.x;
  if (tid >= CB_*N_) return;
  int bl = tid / N_;
  const float* p = x + ((size_t)b0*N_ + (size_t)tid)*3;
  float c[3] = { p[0], p[1], p[2] };
  int vi[3];
  #pragma unroll
  for (int ci=0; ci<3; ++ci){
    int v = (int)floorf(c[ci] / 0.05f);
    v = v < -20 ? -20 : (v > 19 ? 19 : v);
    vi[ci] = v + 20;
  }
  int lin = (vi[0]*G_ + vi[1])*G_ + vi[2];
  double* fs = fsum + (size_t)bl*24*64000 + lin;
  const float PI_F = 3.14159265358979323846f;
  #pragma unroll
  for (int ci=0; ci<3; ++ci){
    double ang = (double)c[ci] * (double)PI_F;
    double s = sin(ang), co = cos(ang);
    #pragma unroll
    for (int k=0; k<4; ++k){
      atomicAdd(fs + (size_t)(ci*8 + k)    *64000, s);
      atomicAdd(fs + (size_t)(ci*8 + 4 + k)*64000, co);
      double s2 = 2.0*s*co;
      double c2 = co*co - s*s;
      s = s2; co = c2;
    }
  }
  atomicAdd(cnt + (size_t)bl*64000 + lin, 1.0);
}

// pooled mask 40->20 straight from cnt (f32 out, slice pre-offset)
__global__ __launch_bounds__(256) void pool_cnt_m20(const double* __restrict__ cnt,
    float* __restrict__ m20)
{
  int tid = blockIdx.x*256 + threadIdx.x;
  if (tid >= CB_*8000) return;
  int xo = tid % 20; int t = tid/20;
  int yo = t % 20;   t /= 20;
  int zo = t % 20;   int bl = t/20;
  const double* cb = cnt + (size_t)bl*64000;
  float mx = 0.0f;
  for (int dz=0; dz<2; ++dz)
    for (int dy=0; dy<2; ++dy)
      for (int dx=0; dx<2; ++dx)
        if (cb[(size_t)((zo*2+dz)*40 + (yo*2+dy))*40 + (xo*2+dx)] > 0.0) mx = 1.0f;
  m20[(size_t)bl*8000 + (zo*20+yo)*20+xo] = mx;
}

// mask maxpool 2x2x2 f32
__global__ __launch_bounds__(256) void pool_mask_f(const float* __restrict__ m,
    float* __restrict__ mo, int Do, int NB)
{
  long tid = (long)blockIdx.x*256 + threadIdx.x;
  if (tid >= (long)NB*Do*Do*Do) return;
  int Di = Do*2;
  int xo = (int)(tid % Do); long t = tid / Do;
  int yo = (int)(t % Do);   t /= Do;
  int zo = (int)(t % Do);   int b = (int)(t / Do);
  const float* mb = m + (size_t)b*Di*Di*Di;
  float mx = 0.0f;
  for (int dz=0; dz<2; ++dz)
    for (int dy=0; dy<2; ++dy)
      for (int dx=0; dx<2; ++dx)
        mx = fmaxf(mx, mb[(size_t)(zo*2+dz)*Di*Di + (size_t)(yo*2+dy)*Di + (xo*2+dx)]);
  mo[tid] = mx;
}

// ---------------------------------------------------------------------------
// 2. FUSED c1 + LN1 + s1 (r8-audited; fp64 out). One wave per s1 voxel.
// ---------------------------------------------------------------------------
__global__ __launch_bounds__(64) void c1_ln_s1(
    const double* __restrict__ fsum, const double* __restrict__ cnt,
    const float* __restrict__ c1w, const float* __restrict__ c1b,
    const float* __restrict__ g1,  const float* __restrict__ b1,
    const float* __restrict__ s1w, const float* __restrict__ s1b,
    double* __restrict__ out, int lb0)             // out: s1o quarter [8,64,8000]
{
  __shared__ double sfeat[24][64];
  __shared__ double sh1[32][8];
  __shared__ double smask[8];

  int blk = blockIdx.x;
  int xo = blk % 20; int t1 = blk/20;
  int yo = t1 % 20;  t1 /= 20;
  int zo = t1 % 20;  int bl = t1/20;
  int t = threadIdx.x;

  int lz = t >> 4, ly = (t >> 2) & 3, lx = t & 3;
  int gz = zo*2 - 1 + lz, gy = yo*2 - 1 + ly, gx = xo*2 - 1 + lx;
  bool inb = (gz>=0 && gz<40) && (gy>=0 && gy<40) && (gx>=0 && gx<40);
  int vox = (gz*40 + gy)*40 + gx;
  double cv = inb ? cnt[(size_t)bl*64000 + vox] : 0.0;
  double ic = (cv > 0.0) ? 1.0/cv : 0.0;
  const double* fb = fsum + (size_t)bl*24*64000 + (inb ? vox : 0);
  #pragma unroll
  for (int ci=0; ci<24; ++ci)
    sfeat[ci][t] = ic * fb[(size_t)ci*64000];
  if (t < 8){
    int dz=t>>2, dy=(t>>1)&1, dx=t&1;
    double c8 = cnt[(size_t)bl*64000 + (size_t)((zo*2+dz)*40 + (yo*2+dy))*40 + (xo*2+dx)];
    smask[t] = (c8 > 0.0) ? 1.0 : 0.0;
  }
  __syncthreads();

  double pm = fmax(fmax(fmax(smask[0],smask[1]),fmax(smask[2],smask[3])),
                   fmax(fmax(smask[4],smask[5]),fmax(smask[6],smask[7])));
  int ovox = (zo*20 + yo)*20 + xo;
  double* ob = out + (size_t)(lb0+bl)*64*8000 + ovox;
  if (pm == 0.0){
    ob[(size_t)t*8000] = 0.0;
    return;
  }

  int c   = t & 31;
  int svh = t >> 5;
  double acc[4] = {0,0,0,0};
  const float* wc = c1w + (size_t)c*24*27;
  for (int ci=0; ci<24; ++ci){
    const float* wp = wc + ci*27;
    const double* sp = &sfeat[ci][0] + svh*16;
    #pragma unroll
    for (int kz=0; kz<3; ++kz)
    #pragma unroll
    for (int ky=0; ky<3; ++ky)
    #pragma unroll
    for (int kx=0; kx<3; ++kx){
      double wv = (double)wp[(kz*3+ky)*3+kx];
      const double* q = sp + kz*16 + ky*4 + kx;
      acc[0] += wv * q[0];
      acc[1] += wv * q[1];
      acc[2] += wv * q[4];
      acc[3] += wv * q[5];
    }
  }
  double bias = (double)c1b[c], gc = (double)g1[c], bc = (double)b1[c];
  double h[4], rs1[4], rs2[4];
  #pragma unroll
  for (int i=0;i<4;++i){
    h[i] = (acc[i] + bias) * smask[svh*4+i];
    rs1[i] = h[i]; rs2[i] = h[i]*h[i];
  }
  #pragma unroll
  for (int off=1; off<32; off<<=1){
    #pragma unroll
    for (int i=0;i<4;++i){
      rs1[i] += __shfl_xor(rs1[i], off);
      rs2[i] += __shfl_xor(rs2[i], off);
    }
  }
  #pragma unroll
  for (int i=0;i<4;++i){
    double mu  = rs1[i]*(1.0/32.0);
    double var = fmax(rs2[i]*(1.0/32.0) - mu*mu, 0.0);
    double r   = 1.0/sqrt(var + 1e-5);
    double yv  = ((h[i]-mu)*r*gc + bc) * smask[svh*4+i];
    sh1[c][svh*4+i] = fmax(yv, 0.0);
  }
  __syncthreads();

  const float* wo = s1w + (size_t)t*256;
  double s = 0.0;
  #pragma unroll
  for (int ci=0; ci<32; ++ci){
    #pragma unroll
    for (int sv=0; sv<8; ++sv)
      s += (double)wo[ci*8+sv] * sh1[ci][sv];
  }
  ob[(size_t)t*8000] = fmax(s + (double)s1b[t], 0.0);
}

// ---------------------------------------------------------------------------
// MFMA layout probe helpers (hardware D-layout self-detect)
// ---------------------------------------------------------------------------
__device__ __forceinline__ double Pf_(int i,int k){ return (double)(1 + i + 31*k); }
__device__ __forceinline__ double Qf_(int k,int j){ return (double)(2 + 3*j + 7*k); }
__device__ __forceinline__ double Rf_(int m,int n){
  double s = 0.0;
  for (int k=0;k<4;++k) s += Pf_(m,k)*Qf_(k,n);
  return s;
}

// ---------------------------------------------------------------------------
// 3a. MFMA conv, 2x2 outer product, global-B (c2). Per wave: 2 cout-tiles x
//     2 voxel-tiles; per (tap,kq): 2 A + 2 B reads -> 4 mfmas, 4 acc chains.
// ---------------------------------------------------------------------------
template<int TI>
__global__ __launch_bounds__(256) void conv_mfma22(
    const double* __restrict__ in, const float* __restrict__ w,
    const float* __restrict__ bias, double* __restrict__ out,
    int NB, int Cin, int Cout, int D)
{
  __shared__ float wl[TI*32*27];        // [cc][io(32)][tap]
  int spat = D*D*D;
  const int BV = 128;                   // 4 waves x 2 voxel tiles x 16
  int nvt = (spat + BV - 1) / BV;
  int bid = blockIdx.x;
  int vt4 = bid % nvt; int t1 = bid / nvt;
  int cot = t1 % (Cout/32); int b = t1 / (Cout/32);
  int wid = threadIdx.x >> 6;
  int lane = threadIdx.x & 63;
  int li = lane & 15, lk = lane >> 4;

  d4 z = {0.0,0.0,0.0,0.0};
  d4 det = __builtin_amdgcn_mfma_f64_16x16x4f64(Pf_(li,lk), Qf_(lk,li), z, 0,0,0);
  bool m2 = true, m3 = true;
  #pragma unroll
  for (int r=0;r<4;++r){
    m2 = m2 && (fabs(det[r] - Rf_(lk+4*r, li)) < 1e-3);   // D[lk+4r][li]
    m3 = m3 && (fabs(det[r] - Rf_(li, 4*lk+r)) < 1e-3);   // D[li][4lk+r]
  }
  int mode = __all(m2) ? 2 : (__all(m3) ? 3 : 1);

  int vbase = vt4*BV + wid*32;
  int v0 = vbase + li;
  int v1 = vbase + 16 + li;
  bool vok0 = v0 < spat, vok1 = v1 < spat;
  int vc0 = vok0 ? v0 : 0, vc1 = vok1 ? v1 : 0;
  int vz0 = vc0/(D*D), vy0 = (vc0/D)%D, vx0 = vc0%D;
  int vz1 = vc1/(D*D), vy1 = (vc1/D)%D, vx1 = vc1%D;

  const double* inb = in + (size_t)b*Cin*spat;
  d4 acc00 = {0.0,0.0,0.0,0.0};   // co-low , vox0
  d4 acc01 = {0.0,0.0,0.0,0.0};   // co-low , vox1
  d4 acc10 = {0.0,0.0,0.0,0.0};   // co-high, vox0
  d4 acc11 = {0.0,0.0,0.0,0.0};   // co-high, vox1

  for (int ci0 = 0; ci0 < Cin; ci0 += TI){
    for (int idx = threadIdx.x; idx < TI*32*27; idx += 256){
      int tap = idx % 27; int t2 = idx / 27;
      int io = t2 % 32; int cc = t2 / 32;
      wl[(cc*32 + io)*27 + tap] =
          w[((size_t)(cot*32+io)*Cin + (ci0+cc))*27 + tap];
    }
    __syncthreads();
    const double* ipk = inb + (size_t)(ci0 + lk)*spat;
    #pragma unroll
    for (int dz = 0; dz < 3; ++dz){
      #pragma unroll
      for (int dy = 0; dy < 3; ++dy){
        #pragma unroll
        for (int dx = 0; dx < 3; ++dx){
          int tap = (dz*3+dy)*3+dx;
          int zi0 = vz0+dz-1, yi0 = vy0+dy-1, xi0 = vx0+dx-1;
          int zi1 = vz1+dz-1, yi1 = vy1+dy-1, xi1 = vx1+dx-1;
          bool ok0 = vok0 && zi0>=0 && zi0<D && yi0>=0 && yi0<D && xi0>=0 && xi0<D;
          bool ok1 = vok1 && zi1>=0 && zi1<D && yi1>=0 && yi1<D && xi1>=0 && xi1<D;
          int so0 = ok0 ? (zi0*D + yi0)*D + xi0 : 0;
          int so1 = ok1 ? (zi1*D + yi1)*D + xi1 : 0;
          #pragma unroll
          for (int kq = 0; kq < TI/4; ++kq){
            double bv0 = ok0 ? ipk[(size_t)(kq*4)*spat + so0] : 0.0;
            double bv1 = ok1 ? ipk[(size_t)(kq*4)*spat + so1] : 0.0;
            double a0 = (double)wl[((kq*4+lk)*32 + li)*27 + tap];
            double a1 = (double)wl[((kq*4+lk)*32 + 16 + li)*27 + tap];
            acc00 = __builtin_amdgcn_mfma_f64_16x16x4f64(a0, bv0, acc00, 0, 0, 0);
            acc01 = __builtin_amdgcn_mfma_f64_16x16x4f64(a0, bv1, acc01, 0, 0, 0);
            acc10 = __builtin_amdgcn_mfma_f64_16x16x4f64(a1, bv0, acc10, 0, 0, 0);
            acc11 = __builtin_amdgcn_mfma_f64_16x16x4f64(a1, bv1, acc11, 0, 0, 0);
          }
        }
      }
    }
    __syncthreads();
  }

  size_t obb = (size_t)b*Cout*spat;
  if (mode == 2){
    #pragma unroll
    for (int r = 0; r < 4; ++r){
      int co0 = cot*32 + lk + 4*r;                 // D[lk+4r][li]
      int co1 = co0 + 16;
      double bv0 = (double)bias[co0], bv1 = (double)bias[co1];
      if (vok0){
        out[obb + (size_t)co0*spat + v0] = acc00[r] + bv0;
        out[obb + (size_t)co1*spat + v0] = acc10[r] + bv1;
      }
      if (vok1){
        out[obb + (size_t)co0*spat + v1] = acc01[r] + bv0;
        out[obb + (size_t)co1*spat + v1] = acc11[r] + bv1;
      }
    }
  } else if (mode == 3){
    int co0 = cot*32 + li;                         // D[li][4lk+r]
    int co1 = co0 + 16;
    double bv0 = (double)bias[co0], bv1 = (double)bias[co1];
    #pragma unroll
    for (int r = 0; r < 4; ++r){
      int vw0 = vbase + 4*lk + r;
      int vw1 = vbase + 16 + 4*lk + r;
      if (vw0 < spat){
        out[obb + (size_t)co0*spat + vw0] = acc00[r] + bv0;
        out[obb + (size_t)co1*spat + vw0] = acc10[r] + bv1;
      }
      if (vw1 < spat){
        out[obb + (size_t)co0*spat + vw1] = acc01[r] + bv0;
        out[obb + (size_t)co1*spat + vw1] = acc11[r] + bv1;
      }
    }
  } else {
    #pragma unroll
    for (int r = 0; r < 4; ++r){
      int co0 = cot*32 + 4*lk + r;                 // fallback
      int co1 = co0 + 16;
      double bv0 = (double)bias[co0], bv1 = (double)bias[co1];
      if (vok0){
        out[obb + (size_t)co0*spat + v0] = acc00[r] + bv0;
        out[obb + (size_t)co1*spat + v0] = acc10[r] + bv1;
      }
      if (vok1){
        out[obb + (size_t)co0*spat + v1] = acc01[r] + bv0;
        out[obb + (size_t)co1*spat + v1] = acc11[r] + bv1;
      }
    }
  }
}

static void launch_cmf(const double* in, const float* w, const float* bias,
                       double* out, int Cin, int Cout, int D, int NB, hipStream_t st)
{
  int spat = D*D*D;
  int nvt = (spat + 127)/128;
  int grid = NB * (Cout/32) * nvt;
  conv_mfma22<8><<<grid,256,0,st>>>(in, w, bias, out, NB, Cin, Cout, D);
}

// ---------------------------------------------------------------------------
// 3b. MFMA conv, 2x2 outer product, LDS-staged B (c3, D=10). Block = 128
//     linear voxels + halo 111 each side -> sIn[8][350] (22.4 KB).
// ---------------------------------------------------------------------------
__global__ __launch_bounds__(256) void conv_mfma_l22(
    const double* __restrict__ in, const float* __restrict__ w,
    const float* __restrict__ bias, double* __restrict__ out,
    int NB, int Cin, int Cout)
{
  const int D = 10, spat = 1000;
  const int TI = 8, HALO = 111, WIN = 128 + 2*HALO;   // 350
  __shared__ float  wl[TI*32*27];                     // 27,648 B
  __shared__ double sIn[TI][WIN];                     // 22,400 B

  const int BV = 128;
  int nvt = (spat + BV - 1) / BV;                     // 8
  int bid = blockIdx.x;
  int vt4 = bid % nvt; int t1 = bid / nvt;
  int cot = t1 % (Cout/32); int b = t1 / (Cout/32);
  int wid = threadIdx.x >> 6;
  int lane = threadIdx.x & 63;
  int li = lane & 15, lk = lane >> 6 ? 0 : (lane >> 4);
  lk = lane >> 4;

  d4 z = {0.0,0.0,0.0,0.0};
  d4 det = __builtin_amdgcn_mfma_f64_16x16x4f64(Pf_(li,lk), Qf_(lk,li), z, 0,0,0);
  bool m2 = true, m3 = true;
  #pragma unroll
  for (int r=0;r<4;++r){
    m2 = m2 && (fabs(det[r] - Rf_(lk+4*r, li)) < 1e-3);
    m3 = m3 && (fabs(det[r] - Rf_(li, 4*lk+r)) < 1e-3);
  }
  int mode = __all(m2) ? 2 : (__all(m3) ? 3 : 1);

  int blk0 = vt4*BV;
  int vbase = blk0 + wid*32;
  int v0 = vbase + li;
  int v1 = vbase + 16 + li;
  bool vok0 = v0 < spat, vok1 = v1 < spat;
  int vc0 = vok0 ? v0 : 0, vc1 = vok1 ? v1 : 0;
  int vz0 = vc0/(D*D), vy0 = (vc0/D)%D, vx0 = vc0%D;
  int vz1 = vc1/(D*D), vy1 = (vc1/D)%D, vx1 = vc1%D;
  int rb0 = wid*32 + li + HALO;
  int rb1 = rb0 + 16;

  const double* inb = in + (size_t)b*Cin*spat;
  d4 acc00 = {0.0,0.0,0.0,0.0};
  d4 acc01 = {0.0,0.0,0.0,0.0};
  d4 acc10 = {0.0,0.0,0.0,0.0};
  d4 acc11 = {0.0,0.0,0.0,0.0};

  for (int ci0 = 0; ci0 < Cin; ci0 += TI){
    for (int idx = threadIdx.x; idx < TI*32*27; idx += 256){
      int tap = idx % 27; int t2 = idx / 27;
      int io = t2 % 32; int cc = t2 / 32;
      wl[(cc*32 + io)*27 + tap] =
          w[((size_t)(cot*32+io)*Cin + (ci0+cc))*27 + tap];
    }
    for (int idx = threadIdx.x; idx < TI*WIN; idx += 256){
      int rel = idx % WIN; int cin = idx / WIN;
      int g = blk0 - HALO + rel;
      g = g < 0 ? 0 : (g >= spat ? spat-1 : g);
      sIn[cin][rel] = inb[(size_t)(ci0+cin)*spat + g];
    }
    __syncthreads();
    #pragma unroll
    for (int dz = 0; dz < 3; ++dz){
      #pragma unroll
      for (int dy = 0; dy < 3; ++dy){
        #pragma unroll
        for (int dx = 0; dx < 3; ++dx){
          int tap = (dz*3+dy)*3+dx;
          int off = (dz-1)*100 + (dy-1)*10 + (dx-1);
          int zi0 = vz0+dz-1, yi0 = vy0+dy-1, xi0 = vx0+dx-1;
          int zi1 = vz1+dz-1, yi1 = vy1+dy-1, xi1 = vx1+dx-1;
          bool ok0 = vok0 && zi0>=0 && zi0<D && yi0>=0 && yi0<D && xi0>=0 && xi0<D;
          bool ok1 = vok1 && zi1>=0 && zi1<D && yi1>=0 && yi1<D && xi1>=0 && xi1<D;
          int rel0 = rb0 + off, rel1 = rb1 + off;
          #pragma unroll
          for (int kq = 0; kq < TI/4; ++kq){
            double bv0 = ok0 ? sIn[kq*4+lk][rel0] : 0.0;
            double bv1 = ok1 ? sIn[kq*4+lk][rel1] : 0.0;
            double a0 = (double)wl[((kq*4+lk)*32 + li)*27 + tap];
            double a1 = (double)wl[((kq*4+lk)*32 + 16 + li)*27 + tap];
            acc00 = __builtin_amdgcn_mfma_f64_16x16x4f64(a0, bv0, acc00, 0, 0, 0);
            acc01 = __builtin_amdgcn_mfma_f64_16x16x4f64(a0, bv1, acc01, 0, 0, 0);
            acc10 = __builtin_amdgcn_mfma_f64_16x16x4f64(a1, bv0, acc10, 0, 0, 0);
            acc11 = __builtin_amdgcn_mfma_f64_16x16x4f64(a1, bv1, acc11, 0, 0, 0);
          }
        }
      }
    }
    __syncthreads();
  }

  size_t obb = (size_t)b*Cout*spat;
  if (mode == 2){
    #pragma unroll
    for (int r = 0; r < 4; ++r){
      int co0 = cot*32 + lk + 4*r;
      int co1 = co0 + 16;
      double bv0 = (double)bias[co0], bv1 = (double)bias[co1];
      if (vok0){
        out[obb + (size_t)co0*spat + v0] = acc00[r] + bv0;
        out[obb + (size_t)co1*spat + v0] = acc10[r] + bv1;
      }
      if (vok1){
        out[obb + (size_t)co0*spat + v1] = acc01[r] + bv0;
        out[obb + (size_t)co1*spat + v1] = acc11[r] + bv1;
      }
    }
  } else if (mode == 3){
    int co0 = cot*32 + li;
    int co1 = co0 + 16;
    double bv0 = (double)bias[co0], bv1 = (double)bias[co1];
    #pragma unroll
    for (int r = 0; r < 4; ++r){
      int vw0 = vbase + 4*lk + r;
      int vw1 = vbase + 16 + 4*lk + r;
      if (vw0 < spat){
        out[obb + (size_t)co0*spat + vw0] = acc00[r] + bv0;
        out[obb + (size_t)co1*spat + vw0] = acc10[r] + bv1;
      }
      if (vw1 < spat){
        out[obb + (size_t)co0*spat + vw1] = acc01[r] + bv0;
        out[obb + (size_t)co1*spat + vw1] = acc11[r] + bv1;
      }
    }
  } else {
    #pragma unroll
    for (int r = 0; r < 4; ++r){
      int co0 = cot*32 + 4*lk + r;
      int co1 = co0 + 16;
      double bv0 = (double)bias[co0], bv1 = (double)bias[co1];
      if (vok0){
        out[obb + (size_t)co0*spat + v0] = acc00[r] + bv0;
        out[obb + (size_t)co1*spat + v0] = acc10[r] + bv1;
      }
      if (vok1){
        out[obb + (size_t)co0*spat + v1] = acc01[r] + bv0;
        out[obb + (size_t)co1*spat + v1] = acc11[r] + bv1;
      }
    }
  }
}

static void launch_cmf_l(const double* in, const float* w, const float* bias,
                         double* out, int Cin, int Cout, int NB, hipStream_t st)
{
  int nvt = (1000 + 127)/128;
  int grid = NB * (Cout/32) * nvt;
  conv_mfma_l22<<<grid,256,0,st>>>(in, w, bias, out, NB, Cin, Cout);
}

// ---------------------------------------------------------------------------
// 4. conv3d, LDS-staged f32 weights, fp64 VALU math (s2, c4)
// ---------------------------------------------------------------------------
template<int K, int S, int P, int XT, int CT, int CGB, int TI,
         bool MMUL, bool RELU_, bool PARTIAL>
__global__ __launch_bounds__(256) void conv_lds(
    const double* __restrict__ in, const float* __restrict__ w,
    const float* __restrict__ bias, const float* __restrict__ mask,
    double* __restrict__ out, int NB, int Cin, int Din, int Cout, int Dout,
    int ncic, int cich)
{
  const int K3 = K*K*K;
  const int SP = 256/CGB;
  const int NR = (XT-1)*S + K;
  __shared__ float wl[CGB*CT][TI*K3];

  int tilesx = (Dout + XT - 1)/XT;
  int spat = tilesx*Dout*Dout;
  int nsb = (spat + SP - 1)/SP;
  int bid = blockIdx.x;
  int cic = 0;
  if (PARTIAL){ cic = bid % ncic; bid /= ncic; }
  int sb = bid % nsb;  int t1 = bid / nsb;
  int ncgo = Cout/(CT*CGB);
  int cgo = t1 % ncgo; int b = t1 / ncgo;
  int ciBeg = PARTIAL ? cic*cich : 0;
  int ciEnd = PARTIAL ? ciBeg + cich : Cin;

  int lc = threadIdx.x / SP;
  int sp = threadIdx.x % SP;
  int sidx = sb*SP + sp;
  bool act = sidx < spat;
  int sc = act ? sidx : 0;
  int tx = sc % tilesx;
  int y  = (sc/tilesx) % Dout;
  int z  = sc/(tilesx*Dout);
  int x0 = tx*XT;
  int co0 = (cgo*CGB + lc)*CT;

  int DD = Din*Din;
  const double* inb = in + (size_t)b*Cin*Din*DD;
  const int wcs = Cin*K3;

  double acc[CT][XT];
  #pragma unroll
  for (int c=0;c<CT;++c){
    double bv = PARTIAL ? 0.0 : (double)bias[co0+c];
    #pragma unroll
    for (int i=0;i<XT;++i) acc[c][i]=bv;
  }

  for (int ci0=ciBeg; ci0<ciEnd; ci0+=TI){
    const int cnt_w = CGB*CT*TI*K3;
    for (int idx = threadIdx.x; idx < cnt_w; idx += 256){
      int k  = idx % K3; int t2 = idx / K3;
      int cil= t2 % TI;  int cr = t2 / TI;
      int co = cgo*CGB*CT + cr;
      float v = 0.0f;
      if (ci0+cil < ciEnd) v = w[(size_t)co*wcs + (size_t)(ci0+cil)*K3 + k];
      wl[cr][cil*K3 + k] = v;
    }
    __syncthreads();
    int tmax = min(TI, ciEnd-ci0);
    for (int cil=0; cil<tmax; ++cil){
      const double* inc = inb + (size_t)(ci0+cil)*Din*DD;
      #pragma unroll
      for (int dz=0; dz<K; ++dz){
        int zi = z*S + dz - P;
        if (zi < 0 || zi >= Din) continue;
        #pragma unroll
        for (int dy=0; dy<K; ++dy){
          int yi = y*S + dy - P;
          if (yi < 0 || yi >= Din) continue;
          const double* row = inc + (size_t)zi*DD + (size_t)yi*Din;
          double rv[NR];
          #pragma unroll
          for (int r=0;r<NR;++r){
            int xi = x0*S + r - P;
            rv[r] = (xi>=0 && xi<Din) ? row[xi] : 0.0;
          }
          #pragma unroll
          for (int dx=0; dx<K; ++dx){
            double wv[CT];
            #pragma unroll
            for (int c=0;c<CT;++c)
              wv[c] = (double)wl[lc*CT+c][cil*K3 + (dz*K+dy)*K + dx];
            #pragma unroll
            for (int i=0;i<XT;++i)
              #pragma unroll
              for (int c=0;c<CT;++c) acc[c][i] += wv[c]*rv[i*S+dx];
          }
        }
      }
    }
    __syncthreads();
  }

  if (act){
    int oDD = Dout*Dout;
    size_t chunk_off = PARTIAL ? (size_t)cic*NB*Cout*Dout*oDD : 0;
    size_t ob = chunk_off + (size_t)b*Cout*Dout*oDD + (size_t)z*oDD + (size_t)y*Dout;
    #pragma unroll
    for (int i=0;i<XT;++i){
      int xo = x0+i;
      if (xo >= Dout) continue;
      double mv = 1.0;
      if (MMUL) mv = (double)mask[(size_t)b*Dout*oDD + (size_t)z*oDD + (size_t)y*Dout + xo];
      #pragma unroll
      for (int c=0;c<CT;++c){
        double v = acc[c][i];
        if (MMUL) v *= mv;
        if (RELU_) v = fmax(v,0.0);
        out[ob + (size_t)(co0+c)*Dout*oDD + xo] = v;
      }
    }
  }
}

template<int K,int S,int P,int XT,int CT,int CGB,int TI,bool MM,bool RL,bool PART>
static void launch_conv(const double* in, const float* w, const float* bias,
                        const float* mask, double* out,
                        int Cin, int Din, int Cout, int Dout, int NB,
                        int ncic, hipStream_t st)
{
  const int SP = 256/CGB;
  int tilesx = (Dout+XT-1)/XT;
  int spat = tilesx*Dout*Dout;
  int nsb = (spat + SP - 1)/SP;
  long grid = (long)(PART?ncic:1) * NB * (Cout/(CT*CGB)) * nsb;
  conv_lds<K,S,P,XT,CT,CGB,TI,MM,RL,PART><<<(int)grid,256,0,st>>>(
      in,w,bias,mask,out,NB,Cin,Din,Cout,Dout,ncic,Cin/(PART?ncic:1));
}

// sum NCIC c4 partials + bias + relu -> c4o
__global__ __launch_bounds__(256) void c4_reduce(const double* __restrict__ part,
    const float* __restrict__ bias, double* __restrict__ out, int NB, int ncic)
{
  long tid = (long)blockIdx.x*256 + threadIdx.x;
  long total = (long)NB*1024*64;
  if (tid >= total) return;
  int co = (int)((tid >> 6) & 1023);
  double s = (double)bias[co];
  for (int c=0; c<ncic; ++c) s += part[(size_t)c*total + tid];
  out[tid] = fmax(s, 0.0);
}

// ---------------------------------------------------------------------------
// 5. s4: one wave per (b,co), 8 outputs
// ---------------------------------------------------------------------------
__global__ __launch_bounds__(256) void s4_wave(const double* __restrict__ c4o,
    const float* __restrict__ w, const float* __restrict__ bias,
    double* __restrict__ out, int NB)
{
  long gt = (long)blockIdx.x*256 + threadIdx.x;
  int wid = (int)(gt >> 6);
  int lane = threadIdx.x & 63;
  if (wid >= NB*1024) return;
  int co = wid & 1023; int b = wid >> 10;
  const double* ib = c4o + (size_t)b*1024*64;
  const float* wp = w + (size_t)co*8192;
  double acc[8] = {0,0,0,0,0,0,0,0};
  for (int k=lane; k<8192; k+=64){
    double wv = (double)wp[k];
    int ci = k>>3, sv = k&7;
    int dz = sv>>2, dy=(sv>>1)&1, dx=sv&1;
    const double* icp = ib + (size_t)ci*64;
    #pragma unroll
    for (int v=0; v<8; ++v){
      int zo=v>>2, yo=(v>>1)&1, xo=v&1;
      acc[v] += wv * icp[((zo*2+dz)*4+(yo*2+dy))*4 + (xo*2+dx)];
    }
  }
  #pragma unroll
  for (int v=0;v<8;++v){
    double a = acc[v];
    #pragma unroll
    for (int off=32;off>0;off>>=1) a += __shfl_down(a, off);
    if (lane==0) out[((size_t)b*1024+co)*8 + v] = a + (double)bias[co];
  }
}

// ---------------------------------------------------------------------------
// 6. channel LayerNorm: fp64 x, f32 params/mask, two-pass (applies mask)
// ---------------------------------------------------------------------------
__global__ __launch_bounds__(256) void ln_chan_d(double* __restrict__ x,
    const float* __restrict__ g, const float* __restrict__ bt,
    const float* __restrict__ mask, int C, int V, int NB)
{
  long tid = (long)blockIdx.x*256 + threadIdx.x;
  if (tid >= (long)NB*V) return;
  int b = (int)(tid / V);
  int v = (int)(tid - (long)b*V);
  double* xp = x + (size_t)b*C*V + v;
  double s = 0.0;
  for (int c=0; c<C; ++c) s += xp[(size_t)c*V];
  double mu = s / C;
  double s2 = 0.0;
  for (int c=0; c<C; ++c){ double d = xp[(size_t)c*V] - mu; s2 += d*d; }
  double r  = 1.0/sqrt(s2 / C + 1e-5);
  double mv = (double)mask[tid];
  for (int c=0; c<C; ++c){
    double yv = ((xp[(size_t)c*V] - mu) * r * (double)g[c] + (double)bt[c]) * mv;
    xp[(size_t)c*V] = fmax(yv, 0.0);
  }
}

// ---------------------------------------------------------------------------
// 7. head — fp64
// ---------------------------------------------------------------------------
__global__ __launch_bounds__(256) void ln_vec(double* __restrict__ h,
    const float* __restrict__ g, const float* __restrict__ bt)
{
  __shared__ double red[256];
  int b = blockIdx.x, t = threadIdx.x;
  double* hp = h + (size_t)b*8192;
  double s = 0.0;
  for (int k=t; k<8192; k+=256) s += hp[k];
  red[t] = s; __syncthreads();
  for (int o=128; o>0; o>>=1){ if (t<o) red[t] += red[t+o]; __syncthreads(); }
  double mu = red[0] / 8192.0;  __syncthreads();
  double s2 = 0.0;
  for (int k=t; k<8192; k+=256){ double d = hp[k]-mu; s2 += d*d; }
  red[t] = s2; __syncthreads();
  for (int o=128; o>0; o>>=1){ if (t<o) red[t] += red[t+o]; __syncthreads(); }
  double r = 1.0/sqrt(red[0]/8192.0 + 1e-5);
  for (int k=t; k<8192; k+=256)
    hp[k] = fmax((hp[k]-mu)*r*(double)g[k] + (double)bt[k], 0.0);
}

__global__ __launch_bounds__(256) void fc_wave(const double* __restrict__ h,
    const float* __restrict__ w, const float* __restrict__ bias,
    double* __restrict__ out, int Kdim, int O, int relu)
{
  long gt = (long)blockIdx.x*256 + threadIdx.x;
  int wid  = (int)(gt >> 6);
  int lane = threadIdx.x & 63;
  if (wid >= B_*O) return;
  int b = wid / O, o = wid - b*O;
  const double* hp = h + (size_t)b*Kdim;
  const float*  wp = w + (size_t)o*Kdim;
  double acc = 0.0;
  for (int k=lane; k<Kdim; k+=64) acc += hp[k]*(double)wp[k];
  #pragma unroll
  for (int off=32; off>0; off>>=1) acc += __shfl_down(acc, off);
  if (lane == 0){
    double v = acc + (double)bias[o];
    if (relu) v = fmax(v, 0.0);
    out[(size_t)b*O + o] = v;
  }
}

__global__ __launch_bounds__(64) void lsm_out(const double* __restrict__ logits,
    float* __restrict__ out)
{
  int b = threadIdx.x;
  if (b >= B_) return;
  const double* lp = logits + (size_t)b*40;
  double m = lp[0];
  for (int i=1; i<40; ++i) m = lp[i] > m ? lp[i] : m;
  double s = 0.0;
  for (int i=0; i<40; ++i) s += exp(lp[i]-m);
  double ls = log(s);
  for (int i=0; i<40; ++i) out[(size_t)b*40+i] = (float)(lp[i] - m - ls);
}

// ---------------------------------------------------------------------------
extern "C" void kernel_launch(void* const* d_in, const int* in_sizes, int n_in,
                              void* d_out, int out_size, void* d_ws, size_t ws_size,
                              hipStream_t stream)
{
  if (ws_size < (size_t)WS_NEEDED) return;

  const float* x   = (const float*)d_in[0];
  const float* c1w = (const float*)d_in[1];  const float* c1b = (const float*)d_in[2];
  const float* g1  = (const float*)d_in[3];  const float* b1  = (const float*)d_in[4];
  const float* s1w = (const float*)d_in[5];  const float* s1b = (const float*)d_in[6];
  const float* c2w = (const float*)d_in[7];  const float* c2b = (const float*)d_in[8];
  const float* g2  = (const float*)d_in[9];  const float* b2  = (const float*)d_in[10];
  const float* s2w = (const float*)d_in[11]; const float* s2b = (const float*)d_in[12];
  const float* c3w = (const float*)d_in[13]; const float* c3b = (const float*)d_in[14];
  const float* g3  = (const float*)d_in[15]; const float* b3  = (const float*)d_in[16];
  const float* c4w = (const float*)d_in[17]; const float* c4b = (const float*)d_in[18];
  const float* s4w = (const float*)d_in[19]; const float* s4b = (const float*)d_in[20];
  const float* g4  = (const float*)d_in[21]; const float* b4  = (const float*)d_in[22];
  const float* f1w = (const float*)d_in[23]; const float* f1b = (const float*)d_in[24];
  const float* f2w = (const float*)d_in[25]; const float* f2b = (const float*)d_in[26];

  char* ws = (char*)d_ws;
  double* s1o = (double*)(ws + OFF_S1O);
  double* s2o = (double*)(ws + OFF_S2O);
  double* part= (double*)(ws + OFF_PART);
  double* c4o = (double*)(ws + OFF_C4O);
  double* c2o = (double*)(ws + OFF_C2O);
  double* c3o = (double*)(ws + OFF_C3O);
  double* fsum= (double*)(ws + OFF_FS);
  double* cnt = (double*)(ws + OFF_CNT);
  float*  m20 = (float*)(ws + OFF_M20);
  float*  m10 = (float*)(ws + OFF_M10);
  double* s4o = (double*)(ws + OFF_S4O);
  double* fc1o= (double*)(ws + OFF_FC1);
  double* logd= (double*)(ws + OFF_LOG);

  for (int q = 0; q < 4; ++q){
    int qb0 = q * QB_;

    // ---- stage 1: 2 scatter-chunks of 4 batches -> fused c1/LN1/s1 ----
    for (int sc = 0; sc < QB_/CB_; ++sc){
      int b0  = qb0 + sc*CB_;
      int lb0 = sc*CB_;
      hipMemsetAsync(ws + OFF_FS, 0, (size_t)CB_*24*64000*8 + (size_t)CB_*64000*8, stream);
      encode_scatter<<<cdiv((long)CB_*N_,256),256,0,stream>>>(x, fsum, cnt, b0);
      pool_cnt_m20  <<<cdiv((long)CB_*8000,256),256,0,stream>>>(cnt, m20 + (size_t)b0*8000);
      c1_ln_s1<<<CB_*8000, 64, 0, stream>>>(fsum, cnt, c1w, c1b, g1, b1,
                                            s1w, s1b, s1o, lb0);
    }
    pool_mask_f<<<cdiv((long)QB_*1000,256),256,0,stream>>>(
        m20 + (size_t)qb0*8000, m10 + (size_t)qb0*1000, 10, QB_);

    // ---- stage 2: c2 via fp64 MFMA 2x2 (global-B) + LN2 + s2 ----
    launch_cmf(s1o, c2w, c2b, c2o, 64, 128, 20, QB_, stream);
    ln_chan_d<<<cdiv((long)QB_*8000,256),256,0,stream>>>(
        c2o, g2, b2, m20 + (size_t)qb0*8000, 128, 8000, QB_);
    launch_conv<2,2,0, 2,8, 1,128, true,true,false>(c2o, s2w, s2b,
        m10 + (size_t)qb0*1000, s2o, 128, 20, 256, 10, QB_, 1, stream);

    // ---- stage 3: c3 via fp64 MFMA 2x2 (LDS-staged B) + LN3 ----
    launch_cmf_l(s2o, c3w, c3b, c3o, 256, 512, QB_, stream);
    ln_chan_d<<<cdiv((long)QB_*1000,256),256,0,stream>>>(
        c3o, g3, b3, m10 + (size_t)qb0*1000, 512, 1000, QB_);

    // ---- stage 4: c4 partial (4 Cin-chunks) + reduce(relu) ; s4 ----
    launch_conv<3,2,0, 2,4, 8,8, false,false,true>(c3o, c4w, c4b, nullptr,
        part, 512, 10, 1024, 4, QB_, 4, stream);
    c4_reduce<<<cdiv((long)QB_*1024*64,256),256,0,stream>>>(part, c4b, c4o, QB_, 4);
    s4_wave<<<cdiv((long)QB_*1024*64,256),256,0,stream>>>(
        c4o, s4w, s4b, s4o + (size_t)qb0*8192, QB_);
  }

  // ---- head (fp64) ----
  ln_vec<<<B_,256,0,stream>>>(s4o, g4, b4);
  fc_wave<<<cdiv((long)B_*1024*64,256),256,0,stream>>>(s4o, f1w, f1b, fc1o, 8192, 1024, 1);
  fc_wave<<<cdiv((long)B_*40*64,256),  256,0,stream>>>(fc1o, f2w, f2b, logd, 1024, 40, 0);
  lsm_out<<<1,64,0,stream>>>(logd, (float*)d_out);
}